// Round 1
// baseline (7200.794 us; speedup 1.0000x reference)
//
#include <hip/hip_runtime.h>
#include <hip/hip_bf16.h>
#include <math.h>

// Problem constants
#define D_MODEL 768
#define D_FF    3072
#define N_HEAD  12
#define HEAD_D  64
#define BATCH   2
#define SEQ     2048

// ---------------- GEMM: C[m,n] = sum_k A[m,k] * W[n,k] (+bias, +res / gelu) ---------
// A: [M,K] row-major, W: [N,K] row-major (torch Linear weight), both k-contiguous (NT).
// mode 0: out = acc + bias
// mode 1: out = acc + bias + res[m*N+n]
// mode 2: out = gelu(acc + bias)   (exact gelu, erf)
#define BM 64
#define BN 64
#define BKT 32
#define LDS_STRIDE 72   // 72 % 32 == 8 -> transpose-store spreads banks; 16B aligned rows

__global__ __launch_bounds__(256) void gemm_nt(
    const float* __restrict__ A, const float* __restrict__ W,
    const float* __restrict__ bias, const float* __restrict__ res,
    float* __restrict__ out, int M, int N, int K, int mode)
{
    __shared__ __align__(16) float As[BKT][LDS_STRIDE];
    __shared__ __align__(16) float Bs[BKT][LDS_STRIDE];

    const int t  = threadIdx.x;
    const int tx = t & 15;        // 16 cols of threads
    const int ty = t >> 4;        // 16 rows of threads
    const int bm = blockIdx.y * BM;
    const int bn = blockIdx.x * BN;

    float acc[4][4] = {{0.f}};

    const float* Ab = A + (size_t)bm * K;
    const float* Wb = W + (size_t)bn * K;

    for (int k0 = 0; k0 < K; k0 += BKT) {
        // Cooperative load: 64 rows x 32 k for both tiles, float4 per access.
        #pragma unroll
        for (int i = 0; i < 2; i++) {
            int f   = t + i * 256;      // 0..511
            int row = f >> 3;           // 0..63
            int k4  = (f & 7) << 2;     // 0,4,...,28
            float4 av = *(const float4*)(Ab + (size_t)row * K + k0 + k4);
            As[k4 + 0][row] = av.x;
            As[k4 + 1][row] = av.y;
            As[k4 + 2][row] = av.z;
            As[k4 + 3][row] = av.w;
            float4 wv = *(const float4*)(Wb + (size_t)row * K + k0 + k4);
            Bs[k4 + 0][row] = wv.x;
            Bs[k4 + 1][row] = wv.y;
            Bs[k4 + 2][row] = wv.z;
            Bs[k4 + 3][row] = wv.w;
        }
        __syncthreads();

        #pragma unroll
        for (int kk = 0; kk < BKT; kk++) {
            float4 a4 = *(const float4*)&As[kk][ty << 2];
            float4 b4 = *(const float4*)&Bs[kk][tx << 2];
            float ar[4] = {a4.x, a4.y, a4.z, a4.w};
            float br[4] = {b4.x, b4.y, b4.z, b4.w};
            #pragma unroll
            for (int i = 0; i < 4; i++)
                #pragma unroll
                for (int j = 0; j < 4; j++)
                    acc[i][j] = fmaf(ar[i], br[j], acc[i][j]);
        }
        __syncthreads();
    }

    // epilogue
    #pragma unroll
    for (int i = 0; i < 4; i++) {
        int m = bm + (ty << 2) + i;
        #pragma unroll
        for (int j = 0; j < 4; j++) {
            int n = bn + (tx << 2) + j;
            float v = acc[i][j] + bias[n];
            if (mode == 1) {
                v += res[(size_t)m * N + n];
            } else if (mode == 2) {
                v = 0.5f * v * (1.0f + erff(v * 0.70710678118654752f));
            }
            out[(size_t)m * N + n] = v;
        }
    }
}

// ---------------- Attention: one wave per (b,h,query-row), online softmax ----------
// q,k,v layout: [B*S, 768] with head h occupying columns h*64..h*64+63.
// out same layout (== einsum('bhqk,bhkd->bqhd').reshape(B,S,D)).
__global__ __launch_bounds__(256) void attn_kernel(
    const float* __restrict__ q, const float* __restrict__ k,
    const float* __restrict__ v, const float* __restrict__ mask,
    float* __restrict__ out)
{
    const int wave = threadIdx.x >> 6;
    const int lane = threadIdx.x & 63;
    const int r  = blockIdx.x * 4 + wave;     // 0 .. B*H*S-1
    const int qi = r % SEQ;
    const int bh = r / SEQ;
    const int h  = bh % N_HEAD;
    const int b  = bh / N_HEAD;

    const float* qp = q + ((size_t)(b * SEQ + qi) * D_MODEL + h * HEAD_D);
    const float  qv = qp[lane] * 0.125f;   // fold 1/sqrt(64)

    const float* kbase = k + (size_t)b * SEQ * D_MODEL + h * HEAD_D;
    const float* vbase = v + (size_t)b * SEQ * D_MODEL + h * HEAD_D;
    const float* mbase = mask + (size_t)b * SEQ;

    float mx = -INFINITY, l = 0.f, o = 0.f;
    for (int j = 0; j < SEQ; j++) {
        float s = qv * kbase[(size_t)j * D_MODEL + lane];
        #pragma unroll
        for (int off = 32; off >= 1; off >>= 1)
            s += __shfl_xor(s, off, 64);
        s -= 10000.0f * (1.0f - mbase[j]);
        float mn = fmaxf(mx, s);
        float sc = __expf(mx - mn);           // first iter: exp(-inf)=0
        float p  = __expf(s - mn);
        l = l * sc + p;
        o = o * sc + p * vbase[(size_t)j * D_MODEL + lane];
        mx = mn;
    }
    out[(size_t)(b * SEQ + qi) * D_MODEL + h * HEAD_D + lane] = o / l;
}

// ---------------- LayerNorm over 768, one block (256 thr) per token ----------------
__global__ __launch_bounds__(256) void ln_kernel(
    const float* __restrict__ in, const float* __restrict__ g,
    const float* __restrict__ be, float* __restrict__ out)
{
    const int row = blockIdx.x;
    const int t   = threadIdx.x;
    const float* rp = in + (size_t)row * D_MODEL;

    float vals[3];
    float s = 0.f, s2 = 0.f;
    #pragma unroll
    for (int i = 0; i < 3; i++) {
        float x = rp[t + i * 256];
        vals[i] = x;
        s += x; s2 += x * x;
    }
    #pragma unroll
    for (int off = 32; off >= 1; off >>= 1) {
        s  += __shfl_xor(s,  off, 64);
        s2 += __shfl_xor(s2, off, 64);
    }
    __shared__ float rs[4], rs2[4];
    __shared__ float mu_s, rstd_s;
    const int wave = t >> 6, lane = t & 63;
    if (lane == 0) { rs[wave] = s; rs2[wave] = s2; }
    __syncthreads();
    if (t == 0) {
        float S1 = rs[0] + rs[1] + rs[2] + rs[3];
        float S2 = rs2[0] + rs2[1] + rs2[2] + rs2[3];
        float mu  = S1 * (1.0f / D_MODEL);
        float var = S2 * (1.0f / D_MODEL) - mu * mu;
        mu_s = mu;
        rstd_s = rsqrtf(var + 1e-12f);
    }
    __syncthreads();
    const float mu = mu_s, rstd = rstd_s;
    #pragma unroll
    for (int i = 0; i < 3; i++) {
        int c = t + i * 256;
        out[(size_t)row * D_MODEL + c] = g[c] * (vals[i] - mu) * rstd + be[c];
    }
}

extern "C" void kernel_launch(void* const* d_in, const int* in_sizes, int n_in,
                              void* d_out, int out_size, void* d_ws, size_t ws_size,
                              hipStream_t stream)
{
    const float* x    = (const float*)d_in[0];
    const float* mask = (const float*)d_in[1];
    const float* Wq   = (const float*)d_in[2];
    const float* bq   = (const float*)d_in[3];
    const float* Wk   = (const float*)d_in[4];
    const float* bk   = (const float*)d_in[5];
    const float* Wv   = (const float*)d_in[6];
    const float* bv   = (const float*)d_in[7];
    const float* Wp   = (const float*)d_in[8];
    const float* bp   = (const float*)d_in[9];
    const float* g1   = (const float*)d_in[10];
    const float* be1  = (const float*)d_in[11];
    const float* W1   = (const float*)d_in[12];
    const float* bf1  = (const float*)d_in[13];
    const float* W2   = (const float*)d_in[14];
    const float* bf2  = (const float*)d_in[15];
    const float* g2   = (const float*)d_in[16];
    const float* be2  = (const float*)d_in[17];

    const int M = BATCH * SEQ;               // 4096 tokens
    const size_t MD = (size_t)M * D_MODEL;   // 3,145,728 floats

    float* ws  = (float*)d_ws;
    float* q   = ws;                 // [M,768]
    float* kk  = ws + 1 * MD;        // [M,768]
    float* vv  = ws + 2 * MD;        // [M,768]
    float* h   = ws + 3 * MD;        // [M,768] attention out
    float* ff1 = ws;                 // [M,3072] aliases q/k/v/h (dead by then), exactly 4*MD
    float* y0  = ws + 4 * MD;        // [M,768] residual sums (reused for y1)
    float* x1  = ws + 5 * MD;        // [M,768] LN1 output
    // total ws use: 6*MD floats = 75.5 MB

    dim3 blk(256);

    // QKV projections
    gemm_nt<<<dim3(D_MODEL / BN, M / BM), blk, 0, stream>>>(x, Wq, bq, nullptr, q,  M, D_MODEL, D_MODEL, 0);
    gemm_nt<<<dim3(D_MODEL / BN, M / BM), blk, 0, stream>>>(x, Wk, bk, nullptr, kk, M, D_MODEL, D_MODEL, 0);
    gemm_nt<<<dim3(D_MODEL / BN, M / BM), blk, 0, stream>>>(x, Wv, bv, nullptr, vv, M, D_MODEL, D_MODEL, 0);

    // Attention (one wave per query row; 4 rows per block)
    attn_kernel<<<dim3(BATCH * N_HEAD * SEQ / 4), blk, 0, stream>>>(q, kk, vv, mask, h);

    // Output projection + residual:  y0 = h @ Wp^T + bp + x
    gemm_nt<<<dim3(D_MODEL / BN, M / BM), blk, 0, stream>>>(h, Wp, bp, x, y0, M, D_MODEL, D_MODEL, 1);

    // LN1 -> x1
    ln_kernel<<<dim3(M), blk, 0, stream>>>(y0, g1, be1, x1);

    // FFN1 + exact GELU: ff1 = gelu(x1 @ W1^T + bf1)
    gemm_nt<<<dim3(D_FF / BN, M / BM), blk, 0, stream>>>(x1, W1, bf1, nullptr, ff1, M, D_FF, D_MODEL, 2);

    // FFN2 + residual: y1 = ff1 @ W2^T + bf2 + x1   (into y0 buffer)
    gemm_nt<<<dim3(D_MODEL / BN, M / BM), blk, 0, stream>>>(ff1, W2, bf2, x1, y0, M, D_MODEL, D_FF, 1);

    // LN2 -> out
    ln_kernel<<<dim3(M), blk, 0, stream>>>(y0, g2, be2, (float*)d_out);
}

// Round 2
// 2089.660 us; speedup vs baseline: 3.4459x; 3.4459x over previous
//
#include <hip/hip_runtime.h>
#include <hip/hip_bf16.h>
#include <math.h>

// Problem constants
#define D_MODEL 768
#define D_FF    3072
#define N_HEAD  12
#define HEAD_D  64
#define BATCH   2
#define SEQ     2048

// ---------------- GEMM: C[m,n] = sum_k A[m,k] * W[n,k] (+bias, +res / gelu) ---------
#define BM 64
#define BN 64
#define BKT 32
#define LDS_STRIDE 72

__global__ __launch_bounds__(256) void gemm_nt(
    const float* __restrict__ A, const float* __restrict__ W,
    const float* __restrict__ bias, const float* __restrict__ res,
    float* __restrict__ out, int M, int N, int K, int mode)
{
    __shared__ __align__(16) float As[BKT][LDS_STRIDE];
    __shared__ __align__(16) float Bs[BKT][LDS_STRIDE];

    const int t  = threadIdx.x;
    const int tx = t & 15;
    const int ty = t >> 4;
    const int bm = blockIdx.y * BM;
    const int bn = blockIdx.x * BN;

    float acc[4][4] = {{0.f}};

    const float* Ab = A + (size_t)bm * K;
    const float* Wb = W + (size_t)bn * K;

    for (int k0 = 0; k0 < K; k0 += BKT) {
        #pragma unroll
        for (int i = 0; i < 2; i++) {
            int f   = t + i * 256;
            int row = f >> 3;
            int k4  = (f & 7) << 2;
            float4 av = *(const float4*)(Ab + (size_t)row * K + k0 + k4);
            As[k4 + 0][row] = av.x;
            As[k4 + 1][row] = av.y;
            As[k4 + 2][row] = av.z;
            As[k4 + 3][row] = av.w;
            float4 wv = *(const float4*)(Wb + (size_t)row * K + k0 + k4);
            Bs[k4 + 0][row] = wv.x;
            Bs[k4 + 1][row] = wv.y;
            Bs[k4 + 2][row] = wv.z;
            Bs[k4 + 3][row] = wv.w;
        }
        __syncthreads();

        #pragma unroll
        for (int kk = 0; kk < BKT; kk++) {
            float4 a4 = *(const float4*)&As[kk][ty << 2];
            float4 b4 = *(const float4*)&Bs[kk][tx << 2];
            float ar[4] = {a4.x, a4.y, a4.z, a4.w};
            float br[4] = {b4.x, b4.y, b4.z, b4.w};
            #pragma unroll
            for (int i = 0; i < 4; i++)
                #pragma unroll
                for (int j = 0; j < 4; j++)
                    acc[i][j] = fmaf(ar[i], br[j], acc[i][j]);
        }
        __syncthreads();
    }

    #pragma unroll
    for (int i = 0; i < 4; i++) {
        int m = bm + (ty << 2) + i;
        #pragma unroll
        for (int j = 0; j < 4; j++) {
            int n = bn + (tx << 2) + j;
            float v = acc[i][j] + bias[n];
            if (mode == 1) {
                v += res[(size_t)m * N + n];
            } else if (mode == 2) {
                v = 0.5f * v * (1.0f + erff(v * 0.70710678118654752f));
            }
            out[(size_t)m * N + n] = v;
        }
    }
}

// ---------------- Tiled flash attention (fp32, no MFMA yet) ------------------------
// Block: 256 thr = 4 waves, handles one (b,h) and a 64-query tile.
// Each thread owns query row q = lane (its Q row lives in 64 VGPRs).
// Scores phase : thread computes 16 keys (wave wv covers keys wv*16..+16).
// PV phase     : thread accumulates O[q][wv*16 .. +16] (16 VGPRs).
// Softmax state (m,l) replicated per-thread (consistent across the 4 waves
// holding the same lane) with cross-wave reductions via small LDS arrays.
#define KSTR 68   // 68*4=272 bytes/row: 16B-aligned rows, odd*16 so banks rotate
#define PSTR 65   // b32-only accesses; stride%32==1 -> conflict-free

__global__ __launch_bounds__(256) void attn_tiled(
    const float* __restrict__ q, const float* __restrict__ k,
    const float* __restrict__ v, const float* __restrict__ mask,
    float* __restrict__ out)
{
    __shared__ __align__(16) float Ks[64][KSTR];
    __shared__ __align__(16) float Vs[64][KSTR];
    __shared__ float Ps[64][PSTR];
    __shared__ float redmax[4][64];
    __shared__ float redsum[4][64];

    const int t    = threadIdx.x;
    const int lane = t & 63;
    const int wv   = t >> 6;
    const int q0   = blockIdx.x * 64;
    const int bh   = blockIdx.y;
    const int h    = bh % N_HEAD;
    const int b    = bh / N_HEAD;

    const float* qbase = q + (size_t)b * SEQ * D_MODEL + h * HEAD_D;
    const float* kbase = k + (size_t)b * SEQ * D_MODEL + h * HEAD_D;
    const float* vbase = v + (size_t)b * SEQ * D_MODEL + h * HEAD_D;
    const float* mbase = mask + (size_t)b * SEQ;

    // Stage Q tile into Ks (coalesced), then pull own row into registers.
    #pragma unroll
    for (int i = 0; i < 4; i++) {
        int row = (t >> 4) + i * 16;
        int c4  = (t & 15) * 4;
        *(float4*)&Ks[row][c4] =
            *(const float4*)(qbase + (size_t)(q0 + row) * D_MODEL + c4);
    }
    __syncthreads();
    float4 qr[16];
    #pragma unroll
    for (int d4 = 0; d4 < 16; d4++) {
        float4 tv = *(const float4*)&Ks[lane][d4 * 4];
        qr[d4].x = tv.x * 0.125f;  // fold 1/sqrt(64)
        qr[d4].y = tv.y * 0.125f;
        qr[d4].z = tv.z * 0.125f;
        qr[d4].w = tv.w * 0.125f;
    }
    __syncthreads();

    float m_st = -INFINITY, l_st = 0.f;
    float o_acc[16];
    #pragma unroll
    for (int i = 0; i < 16; i++) o_acc[i] = 0.f;
    const int d0  = wv * 16;
    const int kb0 = wv * 16;

    for (int kt = 0; kt < SEQ / 64; kt++) {
        // Stage K,V tiles (coalesced float4)
        #pragma unroll
        for (int i = 0; i < 4; i++) {
            int row = (t >> 4) + i * 16;
            int c4  = (t & 15) * 4;
            *(float4*)&Ks[row][c4] =
                *(const float4*)(kbase + (size_t)(kt * 64 + row) * D_MODEL + c4);
            *(float4*)&Vs[row][c4] =
                *(const float4*)(vbase + (size_t)(kt * 64 + row) * D_MODEL + c4);
        }
        __syncthreads();

        // Scores for my q row vs keys kb0..kb0+15 (K rows broadcast across lanes)
        float s[16];
        float locmax = -INFINITY;
        #pragma unroll
        for (int kk = 0; kk < 16; kk++) {
            int key = kb0 + kk;
            float4 a = {0.f, 0.f, 0.f, 0.f};
            #pragma unroll
            for (int d4 = 0; d4 < 16; d4++) {
                float4 kv = *(const float4*)&Ks[key][d4 * 4];
                a.x = fmaf(qr[d4].x, kv.x, a.x);
                a.y = fmaf(qr[d4].y, kv.y, a.y);
                a.z = fmaf(qr[d4].z, kv.z, a.z);
                a.w = fmaf(qr[d4].w, kv.w, a.w);
            }
            float sc = (a.x + a.y) + (a.z + a.w);
            sc -= 10000.0f * (1.0f - mbase[kt * 64 + key]);
            s[kk] = sc;
            locmax = fmaxf(locmax, sc);
        }
        redmax[wv][lane] = locmax;
        __syncthreads();
        float tm = fmaxf(fmaxf(redmax[0][lane], redmax[1][lane]),
                         fmaxf(redmax[2][lane], redmax[3][lane]));
        float m_new = fmaxf(m_st, tm);
        float alpha = __expf(m_st - m_new);   // first tile: exp(-inf)=0
        float lsum = 0.f;
        #pragma unroll
        for (int kk = 0; kk < 16; kk++) {
            float p = __expf(s[kk] - m_new);
            lsum += p;
            Ps[lane][kb0 + kk] = p;
        }
        redsum[wv][lane] = lsum;
        __syncthreads();
        float ts = (redsum[0][lane] + redsum[1][lane]) +
                   (redsum[2][lane] + redsum[3][lane]);
        l_st = l_st * alpha + ts;
        m_st = m_new;

        #pragma unroll
        for (int dd = 0; dd < 16; dd++) o_acc[dd] *= alpha;

        // PV: O[lane][d0+dd] += sum_k Ps[lane][k] * Vs[k][d0+dd]
        #pragma unroll
        for (int kk2 = 0; kk2 < 64; kk2++) {
            float p = Ps[lane][kk2];
            float4 v0 = *(const float4*)&Vs[kk2][d0];
            float4 v1 = *(const float4*)&Vs[kk2][d0 + 4];
            float4 v2 = *(const float4*)&Vs[kk2][d0 + 8];
            float4 v3 = *(const float4*)&Vs[kk2][d0 + 12];
            o_acc[0]  = fmaf(p, v0.x, o_acc[0]);
            o_acc[1]  = fmaf(p, v0.y, o_acc[1]);
            o_acc[2]  = fmaf(p, v0.z, o_acc[2]);
            o_acc[3]  = fmaf(p, v0.w, o_acc[3]);
            o_acc[4]  = fmaf(p, v1.x, o_acc[4]);
            o_acc[5]  = fmaf(p, v1.y, o_acc[5]);
            o_acc[6]  = fmaf(p, v1.z, o_acc[6]);
            o_acc[7]  = fmaf(p, v1.w, o_acc[7]);
            o_acc[8]  = fmaf(p, v2.x, o_acc[8]);
            o_acc[9]  = fmaf(p, v2.y, o_acc[9]);
            o_acc[10] = fmaf(p, v2.z, o_acc[10]);
            o_acc[11] = fmaf(p, v2.w, o_acc[11]);
            o_acc[12] = fmaf(p, v3.x, o_acc[12]);
            o_acc[13] = fmaf(p, v3.y, o_acc[13]);
            o_acc[14] = fmaf(p, v3.z, o_acc[14]);
            o_acc[15] = fmaf(p, v3.w, o_acc[15]);
        }
        __syncthreads();  // protect Ks/Vs/Ps before next tile's staging
    }

    // Epilogue: out[b, q0+lane, h*64 + d0 .. +16] = O / l
    float inv_l = 1.0f / l_st;
    float* orow = out + (size_t)(b * SEQ + q0 + lane) * D_MODEL + h * HEAD_D + d0;
    #pragma unroll
    for (int dd4 = 0; dd4 < 4; dd4++) {
        float4 w;
        w.x = o_acc[dd4 * 4 + 0] * inv_l;
        w.y = o_acc[dd4 * 4 + 1] * inv_l;
        w.z = o_acc[dd4 * 4 + 2] * inv_l;
        w.w = o_acc[dd4 * 4 + 3] * inv_l;
        *(float4*)(orow + dd4 * 4) = w;
    }
}

// ---------------- LayerNorm over 768, one block (256 thr) per token ----------------
__global__ __launch_bounds__(256) void ln_kernel(
    const float* __restrict__ in, const float* __restrict__ g,
    const float* __restrict__ be, float* __restrict__ out)
{
    const int row = blockIdx.x;
    const int t   = threadIdx.x;
    const float* rp = in + (size_t)row * D_MODEL;

    float vals[3];
    float s = 0.f, s2 = 0.f;
    #pragma unroll
    for (int i = 0; i < 3; i++) {
        float x = rp[t + i * 256];
        vals[i] = x;
        s += x; s2 += x * x;
    }
    #pragma unroll
    for (int off = 32; off >= 1; off >>= 1) {
        s  += __shfl_xor(s,  off, 64);
        s2 += __shfl_xor(s2, off, 64);
    }
    __shared__ float rs[4], rs2[4];
    __shared__ float mu_s, rstd_s;
    const int wave = t >> 6, lane = t & 63;
    if (lane == 0) { rs[wave] = s; rs2[wave] = s2; }
    __syncthreads();
    if (t == 0) {
        float S1 = rs[0] + rs[1] + rs[2] + rs[3];
        float S2 = rs2[0] + rs2[1] + rs2[2] + rs2[3];
        float mu  = S1 * (1.0f / D_MODEL);
        float var = S2 * (1.0f / D_MODEL) - mu * mu;
        mu_s = mu;
        rstd_s = rsqrtf(var + 1e-12f);
    }
    __syncthreads();
    const float mu = mu_s, rstd = rstd_s;
    #pragma unroll
    for (int i = 0; i < 3; i++) {
        int c = t + i * 256;
        out[(size_t)row * D_MODEL + c] = g[c] * (vals[i] - mu) * rstd + be[c];
    }
}

extern "C" void kernel_launch(void* const* d_in, const int* in_sizes, int n_in,
                              void* d_out, int out_size, void* d_ws, size_t ws_size,
                              hipStream_t stream)
{
    const float* x    = (const float*)d_in[0];
    const float* mask = (const float*)d_in[1];
    const float* Wq   = (const float*)d_in[2];
    const float* bq   = (const float*)d_in[3];
    const float* Wk   = (const float*)d_in[4];
    const float* bk   = (const float*)d_in[5];
    const float* Wv   = (const float*)d_in[6];
    const float* bv   = (const float*)d_in[7];
    const float* Wp   = (const float*)d_in[8];
    const float* bp   = (const float*)d_in[9];
    const float* g1   = (const float*)d_in[10];
    const float* be1  = (const float*)d_in[11];
    const float* W1   = (const float*)d_in[12];
    const float* bf1  = (const float*)d_in[13];
    const float* W2   = (const float*)d_in[14];
    const float* bf2  = (const float*)d_in[15];
    const float* g2   = (const float*)d_in[16];
    const float* be2  = (const float*)d_in[17];

    const int M = BATCH * SEQ;
    const size_t MD = (size_t)M * D_MODEL;

    float* ws  = (float*)d_ws;
    float* q   = ws;
    float* kk  = ws + 1 * MD;
    float* vv  = ws + 2 * MD;
    float* h   = ws + 3 * MD;
    float* ff1 = ws;                 // aliases q/k/v/h (dead by then)
    float* y0  = ws + 4 * MD;
    float* x1  = ws + 5 * MD;

    dim3 blk(256);

    gemm_nt<<<dim3(D_MODEL / BN, M / BM), blk, 0, stream>>>(x, Wq, bq, nullptr, q,  M, D_MODEL, D_MODEL, 0);
    gemm_nt<<<dim3(D_MODEL / BN, M / BM), blk, 0, stream>>>(x, Wk, bk, nullptr, kk, M, D_MODEL, D_MODEL, 0);
    gemm_nt<<<dim3(D_MODEL / BN, M / BM), blk, 0, stream>>>(x, Wv, bv, nullptr, vv, M, D_MODEL, D_MODEL, 0);

    attn_tiled<<<dim3(SEQ / 64, BATCH * N_HEAD), blk, 0, stream>>>(q, kk, vv, mask, h);

    gemm_nt<<<dim3(D_MODEL / BN, M / BM), blk, 0, stream>>>(h, Wp, bp, x, y0, M, D_MODEL, D_MODEL, 1);

    ln_kernel<<<dim3(M), blk, 0, stream>>>(y0, g1, be1, x1);

    gemm_nt<<<dim3(D_FF / BN, M / BM), blk, 0, stream>>>(x1, W1, bf1, nullptr, ff1, M, D_FF, D_MODEL, 2);

    gemm_nt<<<dim3(D_MODEL / BN, M / BM), blk, 0, stream>>>(ff1, W2, bf2, x1, y0, M, D_MODEL, D_FF, 1);

    ln_kernel<<<dim3(M), blk, 0, stream>>>(y0, g2, be2, (float*)d_out);
}

// Round 3
// 1045.244 us; speedup vs baseline: 6.8891x; 1.9992x over previous
//
#include <hip/hip_runtime.h>
#include <hip/hip_bf16.h>
#include <math.h>

// Problem constants
#define D_MODEL 768
#define D_FF    3072
#define N_HEAD  12
#define HEAD_D  64
#define BATCH   2
#define SEQ     2048

typedef __attribute__((ext_vector_type(8))) short short8;   // 8 bf16 (4 VGPRs)
typedef __attribute__((ext_vector_type(4))) float f32x4;    // MFMA C/D frag

__device__ inline unsigned short f2bf(float f) {
    union { __hip_bfloat16 b; unsigned short u; } cv;
    cv.b = __float2bfloat16(f);
    return cv.u;
}

__device__ inline void async_load16(const void* g, void* l) {
    __builtin_amdgcn_global_load_lds(
        (const __attribute__((address_space(1))) void*)g,
        (__attribute__((address_space(3))) void*)l, 16, 0, 0);
}

// ---------------- fp32 -> bf16 conversion (vectorized), n % 1024 == 0 --------------
__global__ __launch_bounds__(256) void f32_to_bf16(
    const float* __restrict__ in, unsigned short* __restrict__ out)
{
    int i = (blockIdx.x * 256 + threadIdx.x) * 4;
    float4 v = *(const float4*)(in + i);
    ushort4 o;
    o.x = f2bf(v.x); o.y = f2bf(v.y); o.z = f2bf(v.z); o.w = f2bf(v.w);
    *(ushort4*)(out + i) = o;
}

// ---------------- pack qkv biases into one [2304] fp32 buffer ----------------------
__global__ __launch_bounds__(256) void pack_bias(
    const float* __restrict__ bq, const float* __restrict__ bk,
    const float* __restrict__ bv, float* __restrict__ out)
{
    int i = blockIdx.x * 256 + threadIdx.x;   // 0..2303
    float v = (i < 768) ? bq[i] : (i < 1536) ? bk[i - 768] : bv[i - 1536];
    out[i] = v;
}

// ---------------- bf16 MFMA GEMM (m97 structure) -----------------------------------
// C[m,n] = sum_k A[m,k]*W[n,k]; A:[M,K] bf16, W:[N,K] bf16 (both k-contiguous, NT).
// 128x128 tile, BK=32, 4 waves (2x2), each wave 64x64 via 4x4 frags of 16x16x32.
// mode 0: outf = acc + bias
// mode 1: outf = acc + bias + res
// mode 2: outb = bf16(gelu_exact(acc + bias))
__global__ __launch_bounds__(256) void gemm_bf16(
    const unsigned short* __restrict__ A, int lda,
    const unsigned short* __restrict__ W, int ldw,
    const float* __restrict__ bias,
    const float* __restrict__ res, int ldr,
    float* __restrict__ outf, unsigned short* __restrict__ outb, int ldo,
    int M, int N, int K, int mode)
{
    // row-major tiles, contiguous (global_load_lds order), 16 KB total
    __shared__ unsigned short As[128 * 32];
    __shared__ unsigned short Bs[128 * 32];

    const int t    = threadIdx.x;
    const int lane = t & 63;
    const int wv   = t >> 6;        // 0..3
    const int wm   = wv >> 1;       // wave row (0..1)
    const int wn   = wv & 1;        // wave col (0..1)
    const int bm   = blockIdx.y * 128;
    const int bn   = blockIdx.x * 128;

    const int qd   = lane >> 4;     // quad 0..3 -> k-offset qd*8
    const int l16  = lane & 15;

    f32x4 acc[4][4];
    #pragma unroll
    for (int i = 0; i < 4; i++)
        #pragma unroll
        for (int j = 0; j < 4; j++)
            acc[i][j] = (f32x4){0.f, 0.f, 0.f, 0.f};

    // staging addresses: chunk c covers LDS rows c*16..c*16+15 (row = 32 bf16 = 64B)
    // lane l -> row c*16 + (l>>2), 16B-segment (l&3)
    const int srow = lane >> 2;        // 0..15
    const int sseg = (lane & 3) * 8;   // element offset within row

    for (int k0 = 0; k0 < K; k0 += 32) {
        #pragma unroll
        for (int i = 0; i < 2; i++) {
            int c = wv * 2 + i;
            int r = c * 16 + srow;
            async_load16(A + (size_t)(bm + r) * lda + k0 + sseg, As + c * 512);
            async_load16(W + (size_t)(bn + r) * ldw + k0 + sseg, Bs + c * 512);
        }
        __syncthreads();

        short8 af[4], bf[4];
        #pragma unroll
        for (int mt = 0; mt < 4; mt++) {
            int row = wm * 64 + mt * 16 + l16;
            af[mt] = *(const short8*)(As + row * 32 + qd * 8);
        }
        #pragma unroll
        for (int nt = 0; nt < 4; nt++) {
            int col = wn * 64 + nt * 16 + l16;
            bf[nt] = *(const short8*)(Bs + col * 32 + qd * 8);
        }
        #pragma unroll
        for (int mt = 0; mt < 4; mt++)
            #pragma unroll
            for (int nt = 0; nt < 4; nt++)
                acc[mt][nt] = __builtin_amdgcn_mfma_f32_16x16x32_bf16(
                    af[mt], bf[nt], acc[mt][nt], 0, 0, 0);
        __syncthreads();
    }

    // epilogue: C/D mapping col = lane&15, row = (lane>>4)*4 + reg
    #pragma unroll
    for (int mt = 0; mt < 4; mt++) {
        #pragma unroll
        for (int nt = 0; nt < 4; nt++) {
            int col = bn + wn * 64 + nt * 16 + l16;
            float bv = bias[col];
            #pragma unroll
            for (int r = 0; r < 4; r++) {
                int row = bm + wm * 64 + mt * 16 + qd * 4 + r;
                float v = acc[mt][nt][r] + bv;
                if (mode == 1) {
                    v += res[(size_t)row * ldr + col];
                    outf[(size_t)row * ldo + col] = v;
                } else if (mode == 2) {
                    v = 0.5f * v * (1.0f + erff(v * 0.70710678118654752f));
                    outb[(size_t)row * ldo + col] = f2bf(v);
                } else {
                    outf[(size_t)row * ldo + col] = v;
                }
            }
        }
    }
}

// ---------------- Tiled flash attention (fp32), qkv fused input --------------------
// qkv: [B*S, 2304] fp32; q at col h*64, k at 768+h*64, v at 1536+h*64.
// out h: [B*S, 768] bf16.
#define KSTR 68
#define PSTR 65
#define QKV_LD 2304

__global__ __launch_bounds__(256) void attn_tiled(
    const float* __restrict__ qkv, const float* __restrict__ mask,
    unsigned short* __restrict__ out)
{
    __shared__ __align__(16) float Ks[64][KSTR];
    __shared__ __align__(16) float Vs[64][KSTR];
    __shared__ float Ps[64][PSTR];
    __shared__ float redmax[4][64];
    __shared__ float redsum[4][64];

    const int t    = threadIdx.x;
    const int lane = t & 63;
    const int wv   = t >> 6;
    const int q0   = blockIdx.x * 64;
    const int bh   = blockIdx.y;
    const int h    = bh % N_HEAD;
    const int b    = bh / N_HEAD;

    const float* qbase = qkv + (size_t)b * SEQ * QKV_LD + h * HEAD_D;
    const float* kbase = qbase + 768;
    const float* vbase = qbase + 1536;
    const float* mbase = mask + (size_t)b * SEQ;

    #pragma unroll
    for (int i = 0; i < 4; i++) {
        int row = (t >> 4) + i * 16;
        int c4  = (t & 15) * 4;
        *(float4*)&Ks[row][c4] =
            *(const float4*)(qbase + (size_t)(q0 + row) * QKV_LD + c4);
    }
    __syncthreads();
    float4 qr[16];
    #pragma unroll
    for (int d4 = 0; d4 < 16; d4++) {
        float4 tv = *(const float4*)&Ks[lane][d4 * 4];
        qr[d4].x = tv.x * 0.125f;
        qr[d4].y = tv.y * 0.125f;
        qr[d4].z = tv.z * 0.125f;
        qr[d4].w = tv.w * 0.125f;
    }
    __syncthreads();

    float m_st = -INFINITY, l_st = 0.f;
    float o_acc[16];
    #pragma unroll
    for (int i = 0; i < 16; i++) o_acc[i] = 0.f;
    const int d0  = wv * 16;
    const int kb0 = wv * 16;

    for (int kt = 0; kt < SEQ / 64; kt++) {
        #pragma unroll
        for (int i = 0; i < 4; i++) {
            int row = (t >> 4) + i * 16;
            int c4  = (t & 15) * 4;
            *(float4*)&Ks[row][c4] =
                *(const float4*)(kbase + (size_t)(kt * 64 + row) * QKV_LD + c4);
            *(float4*)&Vs[row][c4] =
                *(const float4*)(vbase + (size_t)(kt * 64 + row) * QKV_LD + c4);
        }
        __syncthreads();

        float s[16];
        float locmax = -INFINITY;
        #pragma unroll
        for (int kk = 0; kk < 16; kk++) {
            int key = kb0 + kk;
            float4 a = {0.f, 0.f, 0.f, 0.f};
            #pragma unroll
            for (int d4 = 0; d4 < 16; d4++) {
                float4 kv = *(const float4*)&Ks[key][d4 * 4];
                a.x = fmaf(qr[d4].x, kv.x, a.x);
                a.y = fmaf(qr[d4].y, kv.y, a.y);
                a.z = fmaf(qr[d4].z, kv.z, a.z);
                a.w = fmaf(qr[d4].w, kv.w, a.w);
            }
            float sc = (a.x + a.y) + (a.z + a.w);
            sc -= 10000.0f * (1.0f - mbase[kt * 64 + key]);
            s[kk] = sc;
            locmax = fmaxf(locmax, sc);
        }
        redmax[wv][lane] = locmax;
        __syncthreads();
        float tm = fmaxf(fmaxf(redmax[0][lane], redmax[1][lane]),
                         fmaxf(redmax[2][lane], redmax[3][lane]));
        float m_new = fmaxf(m_st, tm);
        float alpha = __expf(m_st - m_new);
        float lsum = 0.f;
        #pragma unroll
        for (int kk = 0; kk < 16; kk++) {
            float p = __expf(s[kk] - m_new);
            lsum += p;
            Ps[lane][kb0 + kk] = p;
        }
        redsum[wv][lane] = lsum;
        __syncthreads();
        float ts = (redsum[0][lane] + redsum[1][lane]) +
                   (redsum[2][lane] + redsum[3][lane]);
        l_st = l_st * alpha + ts;
        m_st = m_new;

        #pragma unroll
        for (int dd = 0; dd < 16; dd++) o_acc[dd] *= alpha;

        #pragma unroll
        for (int kk2 = 0; kk2 < 64; kk2++) {
            float p = Ps[lane][kk2];
            float4 v0 = *(const float4*)&Vs[kk2][d0];
            float4 v1 = *(const float4*)&Vs[kk2][d0 + 4];
            float4 v2 = *(const float4*)&Vs[kk2][d0 + 8];
            float4 v3 = *(const float4*)&Vs[kk2][d0 + 12];
            o_acc[0]  = fmaf(p, v0.x, o_acc[0]);
            o_acc[1]  = fmaf(p, v0.y, o_acc[1]);
            o_acc[2]  = fmaf(p, v0.z, o_acc[2]);
            o_acc[3]  = fmaf(p, v0.w, o_acc[3]);
            o_acc[4]  = fmaf(p, v1.x, o_acc[4]);
            o_acc[5]  = fmaf(p, v1.y, o_acc[5]);
            o_acc[6]  = fmaf(p, v1.z, o_acc[6]);
            o_acc[7]  = fmaf(p, v1.w, o_acc[7]);
            o_acc[8]  = fmaf(p, v2.x, o_acc[8]);
            o_acc[9]  = fmaf(p, v2.y, o_acc[9]);
            o_acc[10] = fmaf(p, v2.z, o_acc[10]);
            o_acc[11] = fmaf(p, v2.w, o_acc[11]);
            o_acc[12] = fmaf(p, v3.x, o_acc[12]);
            o_acc[13] = fmaf(p, v3.y, o_acc[13]);
            o_acc[14] = fmaf(p, v3.z, o_acc[14]);
            o_acc[15] = fmaf(p, v3.w, o_acc[15]);
        }
        __syncthreads();
    }

    float inv_l = 1.0f / l_st;
    unsigned short* orow = out + (size_t)(b * SEQ + q0 + lane) * D_MODEL + h * HEAD_D + d0;
    #pragma unroll
    for (int dd4 = 0; dd4 < 4; dd4++) {
        ushort4 w;
        w.x = f2bf(o_acc[dd4 * 4 + 0] * inv_l);
        w.y = f2bf(o_acc[dd4 * 4 + 1] * inv_l);
        w.z = f2bf(o_acc[dd4 * 4 + 2] * inv_l);
        w.w = f2bf(o_acc[dd4 * 4 + 3] * inv_l);
        *(ushort4*)(orow + dd4 * 4) = w;
    }
}

// ---------------- LayerNorm over 768; optional secondary bf16 output ---------------
__global__ __launch_bounds__(256) void ln_kernel(
    const float* __restrict__ in, const float* __restrict__ g,
    const float* __restrict__ be, float* __restrict__ out,
    unsigned short* __restrict__ outb)
{
    const int row = blockIdx.x;
    const int t   = threadIdx.x;
    const float* rp = in + (size_t)row * D_MODEL;

    float vals[3];
    float s = 0.f, s2 = 0.f;
    #pragma unroll
    for (int i = 0; i < 3; i++) {
        float x = rp[t + i * 256];
        vals[i] = x;
        s += x; s2 += x * x;
    }
    #pragma unroll
    for (int off = 32; off >= 1; off >>= 1) {
        s  += __shfl_xor(s,  off, 64);
        s2 += __shfl_xor(s2, off, 64);
    }
    __shared__ float rs[4], rs2[4];
    __shared__ float mu_s, rstd_s;
    const int wave = t >> 6, lane = t & 63;
    if (lane == 0) { rs[wave] = s; rs2[wave] = s2; }
    __syncthreads();
    if (t == 0) {
        float S1 = rs[0] + rs[1] + rs[2] + rs[3];
        float S2 = rs2[0] + rs2[1] + rs2[2] + rs2[3];
        float mu  = S1 * (1.0f / D_MODEL);
        float var = S2 * (1.0f / D_MODEL) - mu * mu;
        mu_s = mu;
        rstd_s = rsqrtf(var + 1e-12f);
    }
    __syncthreads();
    const float mu = mu_s, rstd = rstd_s;
    #pragma unroll
    for (int i = 0; i < 3; i++) {
        int c = t + i * 256;
        float o = g[c] * (vals[i] - mu) * rstd + be[c];
        out[(size_t)row * D_MODEL + c] = o;
        if (outb) outb[(size_t)row * D_MODEL + c] = f2bf(o);
    }
}

extern "C" void kernel_launch(void* const* d_in, const int* in_sizes, int n_in,
                              void* d_out, int out_size, void* d_ws, size_t ws_size,
                              hipStream_t stream)
{
    const float* x    = (const float*)d_in[0];
    const float* mask = (const float*)d_in[1];
    const float* Wq   = (const float*)d_in[2];
    const float* bq   = (const float*)d_in[3];
    const float* Wk   = (const float*)d_in[4];
    const float* bk   = (const float*)d_in[5];
    const float* Wv   = (const float*)d_in[6];
    const float* bv   = (const float*)d_in[7];
    const float* Wp   = (const float*)d_in[8];
    const float* bp   = (const float*)d_in[9];
    const float* g1   = (const float*)d_in[10];
    const float* be1  = (const float*)d_in[11];
    const float* W1   = (const float*)d_in[12];
    const float* bf1  = (const float*)d_in[13];
    const float* W2   = (const float*)d_in[14];
    const float* bf2  = (const float*)d_in[15];
    const float* g2   = (const float*)d_in[16];
    const float* be2  = (const float*)d_in[17];

    const int M = BATCH * SEQ;   // 4096

    // ---- workspace layout (bytes), total ~83.4 MB ----
    char* ws = (char*)d_ws;
    float*          qkv   = (float*)(ws + 0);                      // [4096,2304] f32 (37.75MB); reused as ff1b bf16
    unsigned short* ff1b  = (unsigned short*)(ws + 0);             // [4096,3072] bf16 (25.2MB) alias
    float*          x1    = (float*)(ws + 37748736);               // [4096,768] f32 (12.6MB)
    unsigned short* xb    = (unsigned short*)(ws + 37748736);      // alias (dead before x1 born)
    unsigned short* hb    = (unsigned short*)(ws + 50331648);      // [4096,768] bf16 (6.3MB)
    unsigned short* x1b   = (unsigned short*)(ws + 50331648);      // alias (hb dead first)
    unsigned short* wqkvb = (unsigned short*)(ws + 56623104);      // [2304,768] bf16
    unsigned short* wpb   = (unsigned short*)(ws + 60162048);      // [768,768]
    unsigned short* w1b   = (unsigned short*)(ws + 61341696);      // [3072,768]
    unsigned short* w2b   = (unsigned short*)(ws + 66060288);      // [768,3072]
    float*          bqkv  = (float*)(ws + 70778880);               // [2304] f32
    float*          y0    = (float*)(ws + 70788096);               // [4096,768] f32 (reused as y1)

    dim3 blk(256);

    // conversions: x and weights -> bf16
    f32_to_bf16<<<dim3(M * D_MODEL / 1024), blk, 0, stream>>>(x, xb);
    f32_to_bf16<<<dim3(589824 / 1024), blk, 0, stream>>>(Wq, wqkvb);
    f32_to_bf16<<<dim3(589824 / 1024), blk, 0, stream>>>(Wk, wqkvb + 589824);
    f32_to_bf16<<<dim3(589824 / 1024), blk, 0, stream>>>(Wv, wqkvb + 1179648);
    f32_to_bf16<<<dim3(589824 / 1024), blk, 0, stream>>>(Wp, wpb);
    f32_to_bf16<<<dim3(2359296 / 1024), blk, 0, stream>>>(W1, w1b);
    f32_to_bf16<<<dim3(2359296 / 1024), blk, 0, stream>>>(W2, w2b);
    pack_bias<<<dim3(9), blk, 0, stream>>>(bq, bk, bv, bqkv);

    // fused QKV GEMM: qkv[M,2304] = xb @ wqkvb^T + bqkv
    gemm_bf16<<<dim3(2304 / 128, M / 128), blk, 0, stream>>>(
        xb, D_MODEL, wqkvb, D_MODEL, bqkv, nullptr, 0,
        qkv, nullptr, 2304, M, 2304, D_MODEL, 0);

    // attention -> hb (bf16)
    attn_tiled<<<dim3(SEQ / 64, BATCH * N_HEAD), blk, 0, stream>>>(qkv, mask, hb);

    // proj + residual: y0 = hb @ wpb^T + bp + x
    gemm_bf16<<<dim3(D_MODEL / 128, M / 128), blk, 0, stream>>>(
        hb, D_MODEL, wpb, D_MODEL, bp, x, D_MODEL,
        y0, nullptr, D_MODEL, M, D_MODEL, D_MODEL, 1);

    // LN1 -> x1 (f32) + x1b (bf16)
    ln_kernel<<<dim3(M), blk, 0, stream>>>(y0, g1, be1, x1, x1b);

    // FFN1 + gelu -> ff1b (bf16)
    gemm_bf16<<<dim3(D_FF / 128, M / 128), blk, 0, stream>>>(
        x1b, D_MODEL, w1b, D_MODEL, bf1, nullptr, 0,
        nullptr, ff1b, D_FF, M, D_FF, D_MODEL, 2);

    // FFN2 + residual: y1 = ff1b @ w2b^T + bf2 + x1  (into y0)
    gemm_bf16<<<dim3(D_MODEL / 128, M / 128), blk, 0, stream>>>(
        ff1b, D_FF, w2b, D_FF, bf2, x1, D_MODEL,
        y0, nullptr, D_MODEL, M, D_MODEL, D_FF, 1);

    // LN2 -> out (f32)
    ln_kernel<<<dim3(M), blk, 0, stream>>>(y0, g2, be2, (float*)d_out, nullptr);
}

// Round 4
// 439.565 us; speedup vs baseline: 16.3817x; 2.3779x over previous
//
#include <hip/hip_runtime.h>
#include <hip/hip_bf16.h>
#include <math.h>

// Problem constants
#define D_MODEL 768
#define D_FF    3072
#define N_HEAD  12
#define HEAD_D  64
#define BATCH   2
#define SEQ     2048
#define QKV_LD  2304

typedef __attribute__((ext_vector_type(8))) short short8;            // 8 bf16 (4 VGPRs)
typedef __attribute__((ext_vector_type(8))) unsigned short ushort8;  // 16B staging
typedef __attribute__((ext_vector_type(4))) float f32x4;             // MFMA C/D frag

__device__ inline unsigned short f2bf(float f) {
    union { __hip_bfloat16 b; unsigned short u; } cv;
    cv.b = __float2bfloat16(f);
    return cv.u;
}

__device__ inline void async_load16(const void* g, void* l) {
    __builtin_amdgcn_global_load_lds(
        (const __attribute__((address_space(1))) void*)g,
        (__attribute__((address_space(3))) void*)l, 16, 0, 0);
}

// ---------------- fused fp32->bf16 conversions + bias pack -------------------------
// blocks: [0,3072) x  [3072,3648) Wq  [3648,4224) Wk  [4224,4800) Wv
//         [4800,5376) Wp  [5376,7680) W1  [7680,9984) W2  [9984] bias pack
__global__ __launch_bounds__(256) void conv_fused(
    const float* __restrict__ x,
    const float* __restrict__ Wq, const float* __restrict__ Wk,
    const float* __restrict__ Wv, const float* __restrict__ Wp,
    const float* __restrict__ W1, const float* __restrict__ W2,
    const float* __restrict__ bq, const float* __restrict__ bk,
    const float* __restrict__ bv,
    unsigned short* __restrict__ xb, unsigned short* __restrict__ wqkvb,
    unsigned short* __restrict__ wpb, unsigned short* __restrict__ w1b,
    unsigned short* __restrict__ w2b, float* __restrict__ bqkv)
{
    int bid = blockIdx.x;
    const float* src; unsigned short* dst; int base;
    if      (bid < 3072) { src = x;  dst = xb;              base = bid;        }
    else if (bid < 3648) { src = Wq; dst = wqkvb;           base = bid - 3072; }
    else if (bid < 4224) { src = Wk; dst = wqkvb + 589824;  base = bid - 3648; }
    else if (bid < 4800) { src = Wv; dst = wqkvb + 1179648; base = bid - 4224; }
    else if (bid < 5376) { src = Wp; dst = wpb;             base = bid - 4800; }
    else if (bid < 7680) { src = W1; dst = w1b;             base = bid - 5376; }
    else if (bid < 9984) { src = W2; dst = w2b;             base = bid - 7680; }
    else {
        for (int j = threadIdx.x; j < QKV_LD; j += 256)
            bqkv[j] = (j < 768) ? bq[j] : (j < 1536) ? bk[j - 768] : bv[j - 1536];
        return;
    }
    int i = (base * 256 + threadIdx.x) * 4;
    float4 v = *(const float4*)(src + i);
    ushort4 o4;
    o4.x = f2bf(v.x); o4.y = f2bf(v.y); o4.z = f2bf(v.z); o4.w = f2bf(v.w);
    *(ushort4*)(dst + i) = o4;
}

// ---------------- bf16 MFMA GEMM (m97 structure) -----------------------------------
// C[m,n] = sum_k A[m,k]*W[n,k]; A:[M,K] bf16, W:[N,K] bf16 (NT).
// mode 0: outf = acc + bias
// mode 1: outf = acc + bias + res
// mode 2: outb = bf16(gelu_exact(acc + bias))
// mode 3: outb = bf16(acc + bias)
__global__ __launch_bounds__(256) void gemm_bf16(
    const unsigned short* __restrict__ A, int lda,
    const unsigned short* __restrict__ W, int ldw,
    const float* __restrict__ bias,
    const float* __restrict__ res, int ldr,
    float* __restrict__ outf, unsigned short* __restrict__ outb, int ldo,
    int M, int N, int K, int mode)
{
    __shared__ unsigned short As[128 * 32];
    __shared__ unsigned short Bs[128 * 32];

    const int t    = threadIdx.x;
    const int lane = t & 63;
    const int wv   = t >> 6;
    const int wm   = wv >> 1;
    const int wn   = wv & 1;
    const int bm   = blockIdx.y * 128;
    const int bn   = blockIdx.x * 128;

    const int qd   = lane >> 4;
    const int l16  = lane & 15;

    f32x4 acc[4][4];
    #pragma unroll
    for (int i = 0; i < 4; i++)
        #pragma unroll
        for (int j = 0; j < 4; j++)
            acc[i][j] = (f32x4){0.f, 0.f, 0.f, 0.f};

    const int srow = lane >> 2;
    const int sseg = (lane & 3) * 8;

    for (int k0 = 0; k0 < K; k0 += 32) {
        #pragma unroll
        for (int i = 0; i < 2; i++) {
            int c = wv * 2 + i;
            int r = c * 16 + srow;
            async_load16(A + (size_t)(bm + r) * lda + k0 + sseg, As + c * 512);
            async_load16(W + (size_t)(bn + r) * ldw + k0 + sseg, Bs + c * 512);
        }
        __syncthreads();

        short8 af[4], bf[4];
        #pragma unroll
        for (int mt = 0; mt < 4; mt++)
            af[mt] = *(const short8*)(As + (wm * 64 + mt * 16 + l16) * 32 + qd * 8);
        #pragma unroll
        for (int nt = 0; nt < 4; nt++)
            bf[nt] = *(const short8*)(Bs + (wn * 64 + nt * 16 + l16) * 32 + qd * 8);
        #pragma unroll
        for (int mt = 0; mt < 4; mt++)
            #pragma unroll
            for (int nt = 0; nt < 4; nt++)
                acc[mt][nt] = __builtin_amdgcn_mfma_f32_16x16x32_bf16(
                    af[mt], bf[nt], acc[mt][nt], 0, 0, 0);
        __syncthreads();
    }

    #pragma unroll
    for (int mt = 0; mt < 4; mt++) {
        #pragma unroll
        for (int nt = 0; nt < 4; nt++) {
            int col = bn + wn * 64 + nt * 16 + l16;
            float bv = bias[col];
            #pragma unroll
            for (int r = 0; r < 4; r++) {
                int row = bm + wm * 64 + mt * 16 + qd * 4 + r;
                float v = acc[mt][nt][r] + bv;
                if (mode == 1) {
                    v += res[(size_t)row * ldr + col];
                    outf[(size_t)row * ldo + col] = v;
                } else if (mode == 2) {
                    v = 0.5f * v * (1.0f + erff(v * 0.70710678118654752f));
                    outb[(size_t)row * ldo + col] = f2bf(v);
                } else if (mode == 3) {
                    outb[(size_t)row * ldo + col] = f2bf(v);
                } else {
                    outf[(size_t)row * ldo + col] = v;
                }
            }
        }
    }
}

// ---------------- MFMA flash attention ---------------------------------------------
// qkv: [B*S, 2304] bf16 (q at h*64, k at 768+h*64, v at 1536+h*64).
// Block = 4 waves, one (b,h), 64-query tile; wave owns 16 queries.
// Per 64-key tile: QK^T (8 mfma) -> softmax (xor-shuffle over 16 lanes) ->
// P via LDS (C-layout -> A-layout) -> PV (8 mfma) with V transposed in LDS.
#define ATT_STR 72   // shorts; 144B row stride (16B-multiple for b128)

__global__ __launch_bounds__(256) void attn_mfma(
    const unsigned short* __restrict__ qkv, const float* __restrict__ mask,
    unsigned short* __restrict__ out)
{
    __shared__ __align__(16) unsigned short Ks[64 * ATT_STR];
    __shared__ __align__(16) unsigned short Vt[64 * ATT_STR];
    __shared__ __align__(16) unsigned short Ps[4 * 16 * ATT_STR];
    __shared__ float Ms[64];

    const int t    = threadIdx.x;
    const int lane = t & 63;
    const int wv   = t >> 6;
    const int l16  = lane & 15;
    const int quad = lane >> 4;
    const int q0   = blockIdx.x * 64;
    const int bh   = blockIdx.y;
    const int h    = bh % N_HEAD;
    const int b    = bh / N_HEAD;

    const unsigned short* qb = qkv + (size_t)b * SEQ * QKV_LD + h * HEAD_D;
    const unsigned short* kb = qb + 768;
    const unsigned short* vb = qb + 1536;

    const int srow = t >> 2;          // staging row 0..63
    const int sc0  = (t & 3) * 16;    // staging col (shorts)

    // ---- stage Q tile, pull A-frags ----
    {
        const ushort8* src = (const ushort8*)(qb + (size_t)(q0 + srow) * QKV_LD + sc0);
        *(ushort8*)(Ks + srow * ATT_STR + sc0)     = src[0];
        *(ushort8*)(Ks + srow * ATT_STR + sc0 + 8) = src[1];
    }
    __syncthreads();
    short8 aq[2];
    aq[0] = *(const short8*)(Ks + (wv * 16 + l16) * ATT_STR + quad * 8);
    aq[1] = *(const short8*)(Ks + (wv * 16 + l16) * ATT_STR + 32 + quad * 8);
    __syncthreads();

    f32x4 o[4];
    #pragma unroll
    for (int i = 0; i < 4; i++) o[i] = (f32x4){0.f, 0.f, 0.f, 0.f};
    float m_st[4] = {-INFINITY, -INFINITY, -INFINITY, -INFINITY};
    float l_st[4] = {0.f, 0.f, 0.f, 0.f};

    unsigned short* Pw = Ps + wv * 16 * ATT_STR;

    for (int kt = 0; kt < SEQ / 64; kt++) {
        const int key0 = kt * 64;
        // ---- stage K (natural) + V (transposed) + mask ----
        {
            const ushort8* ksrc = (const ushort8*)(kb + (size_t)(key0 + srow) * QKV_LD + sc0);
            *(ushort8*)(Ks + srow * ATT_STR + sc0)     = ksrc[0];
            *(ushort8*)(Ks + srow * ATT_STR + sc0 + 8) = ksrc[1];
            const ushort8* vsrc = (const ushort8*)(vb + (size_t)(key0 + srow) * QKV_LD + sc0);
            ushort8 v0 = vsrc[0], v1 = vsrc[1];
            #pragma unroll
            for (int j = 0; j < 8; j++) Vt[(sc0 + j) * ATT_STR + srow] = v0[j];
            #pragma unroll
            for (int j = 0; j < 8; j++) Vt[(sc0 + 8 + j) * ATT_STR + srow] = v1[j];
            if (t < 64) Ms[t] = -10000.0f * (1.0f - mask[b * SEQ + key0 + t]);
        }
        __syncthreads();

        // ---- QK^T: scores 16q x 64k in C-layout ----
        f32x4 sc[4];
        #pragma unroll
        for (int nt = 0; nt < 4; nt++) {
            sc[nt] = (f32x4){0.f, 0.f, 0.f, 0.f};
            short8 bk0 = *(const short8*)(Ks + (nt * 16 + l16) * ATT_STR + quad * 8);
            short8 bk1 = *(const short8*)(Ks + (nt * 16 + l16) * ATT_STR + 32 + quad * 8);
            sc[nt] = __builtin_amdgcn_mfma_f32_16x16x32_bf16(aq[0], bk0, sc[nt], 0, 0, 0);
            sc[nt] = __builtin_amdgcn_mfma_f32_16x16x32_bf16(aq[1], bk1, sc[nt], 0, 0, 0);
        }

        // ---- online softmax (per C-row r; row = quad*4 + r) ----
        float alpha[4];
        float m0 = Ms[l16], m1 = Ms[16 + l16], m2 = Ms[32 + l16], m3 = Ms[48 + l16];
        #pragma unroll
        for (int r = 0; r < 4; r++) {
            float s0 = fmaf(sc[0][r], 0.125f, m0);
            float s1 = fmaf(sc[1][r], 0.125f, m1);
            float s2 = fmaf(sc[2][r], 0.125f, m2);
            float s3 = fmaf(sc[3][r], 0.125f, m3);
            float mx = fmaxf(fmaxf(s0, s1), fmaxf(s2, s3));
            mx = fmaxf(mx, __shfl_xor(mx, 1, 64));
            mx = fmaxf(mx, __shfl_xor(mx, 2, 64));
            mx = fmaxf(mx, __shfl_xor(mx, 4, 64));
            mx = fmaxf(mx, __shfl_xor(mx, 8, 64));
            float mn = fmaxf(m_st[r], mx);
            alpha[r] = __expf(m_st[r] - mn);
            m_st[r]  = mn;
            float p0 = __expf(s0 - mn), p1 = __expf(s1 - mn);
            float p2 = __expf(s2 - mn), p3 = __expf(s3 - mn);
            int qrow = quad * 4 + r;
            Pw[qrow * ATT_STR +      l16] = f2bf(p0);
            Pw[qrow * ATT_STR + 16 + l16] = f2bf(p1);
            Pw[qrow * ATT_STR + 32 + l16] = f2bf(p2);
            Pw[qrow * ATT_STR + 48 + l16] = f2bf(p3);
            float ls = (p0 + p1) + (p2 + p3);
            ls += __shfl_xor(ls, 1, 64);
            ls += __shfl_xor(ls, 2, 64);
            ls += __shfl_xor(ls, 4, 64);
            ls += __shfl_xor(ls, 8, 64);
            l_st[r] = l_st[r] * alpha[r] + ls;
        }

        // ---- rescale O ----
        #pragma unroll
        for (int nt = 0; nt < 4; nt++)
            #pragma unroll
            for (int r = 0; r < 4; r++)
                o[nt][r] *= alpha[r];

        // ---- P (A-layout) from wave-local LDS; PV ----
        short8 pf0 = *(const short8*)(Pw + l16 * ATT_STR + quad * 8);
        short8 pf1 = *(const short8*)(Pw + l16 * ATT_STR + 32 + quad * 8);
        #pragma unroll
        for (int nt = 0; nt < 4; nt++) {
            short8 vt0 = *(const short8*)(Vt + (nt * 16 + l16) * ATT_STR + quad * 8);
            short8 vt1 = *(const short8*)(Vt + (nt * 16 + l16) * ATT_STR + 32 + quad * 8);
            o[nt] = __builtin_amdgcn_mfma_f32_16x16x32_bf16(pf0, vt0, o[nt], 0, 0, 0);
            o[nt] = __builtin_amdgcn_mfma_f32_16x16x32_bf16(pf1, vt1, o[nt], 0, 0, 0);
        }
        __syncthreads();
    }

    // ---- epilogue: out[b, q, h*64+d] = O / l ----
    float inv[4];
    #pragma unroll
    for (int r = 0; r < 4; r++) inv[r] = 1.0f / l_st[r];
    #pragma unroll
    for (int nt = 0; nt < 4; nt++) {
        #pragma unroll
        for (int r = 0; r < 4; r++) {
            int qi = q0 + wv * 16 + quad * 4 + r;
            out[(size_t)(b * SEQ + qi) * D_MODEL + h * HEAD_D + nt * 16 + l16] =
                f2bf(o[nt][r] * inv[r]);
        }
    }
}

// ---------------- LayerNorm over 768; optional secondary bf16 output ---------------
__global__ __launch_bounds__(256) void ln_kernel(
    const float* __restrict__ in, const float* __restrict__ g,
    const float* __restrict__ be, float* __restrict__ out,
    unsigned short* __restrict__ outb)
{
    const int row = blockIdx.x;
    const int t   = threadIdx.x;
    const float* rp = in + (size_t)row * D_MODEL;

    float vals[3];
    float s = 0.f, s2 = 0.f;
    #pragma unroll
    for (int i = 0; i < 3; i++) {
        float x = rp[t + i * 256];
        vals[i] = x;
        s += x; s2 += x * x;
    }
    #pragma unroll
    for (int off = 32; off >= 1; off >>= 1) {
        s  += __shfl_xor(s,  off, 64);
        s2 += __shfl_xor(s2, off, 64);
    }
    __shared__ float rs[4], rs2[4];
    __shared__ float mu_s, rstd_s;
    const int wave = t >> 6, lane = t & 63;
    if (lane == 0) { rs[wave] = s; rs2[wave] = s2; }
    __syncthreads();
    if (t == 0) {
        float S1 = rs[0] + rs[1] + rs[2] + rs[3];
        float S2 = rs2[0] + rs2[1] + rs2[2] + rs2[3];
        float mu  = S1 * (1.0f / D_MODEL);
        float var = S2 * (1.0f / D_MODEL) - mu * mu;
        mu_s = mu;
        rstd_s = rsqrtf(var + 1e-12f);
    }
    __syncthreads();
    const float mu = mu_s, rstd = rstd_s;
    #pragma unroll
    for (int i = 0; i < 3; i++) {
        int c = t + i * 256;
        float o = g[c] * (vals[i] - mu) * rstd + be[c];
        out[(size_t)row * D_MODEL + c] = o;
        if (outb) outb[(size_t)row * D_MODEL + c] = f2bf(o);
    }
}

extern "C" void kernel_launch(void* const* d_in, const int* in_sizes, int n_in,
                              void* d_out, int out_size, void* d_ws, size_t ws_size,
                              hipStream_t stream)
{
    const float* x    = (const float*)d_in[0];
    const float* mask = (const float*)d_in[1];
    const float* Wq   = (const float*)d_in[2];
    const float* bq   = (const float*)d_in[3];
    const float* Wk   = (const float*)d_in[4];
    const float* bk   = (const float*)d_in[5];
    const float* Wv   = (const float*)d_in[6];
    const float* bv   = (const float*)d_in[7];
    const float* Wp   = (const float*)d_in[8];
    const float* bp   = (const float*)d_in[9];
    const float* g1   = (const float*)d_in[10];
    const float* be1  = (const float*)d_in[11];
    const float* W1   = (const float*)d_in[12];
    const float* bf1  = (const float*)d_in[13];
    const float* W2   = (const float*)d_in[14];
    const float* bf2  = (const float*)d_in[15];
    const float* g2   = (const float*)d_in[16];
    const float* be2  = (const float*)d_in[17];

    const int M = BATCH * SEQ;   // 4096

    // ---- workspace layout (bytes), ~70.8 MB total ----
    char* ws = (char*)d_ws;
    unsigned short* qkvb  = (unsigned short*)(ws + 0);         // [4096,2304] bf16 (18.9MB)
    unsigned short* ff1b  = (unsigned short*)(ws + 0);         // [4096,3072] bf16 (25.2MB), qkvb dead
    unsigned short* xb    = (unsigned short*)(ws + 25165824);  // [4096,768] bf16
    unsigned short* hb    = (unsigned short*)(ws + 25165824);  // alias (xb dead after QKV)
    unsigned short* x1b   = (unsigned short*)(ws + 25165824);  // alias (hb dead after proj)
    float*          y0    = (float*)(ws + 31457280);           // [4096,768] f32
    float*          x1    = (float*)(ws + 44040192);           // [4096,768] f32
    unsigned short* wqkvb = (unsigned short*)(ws + 56623104);  // [2304,768] bf16
    unsigned short* wpb   = (unsigned short*)(ws + 60162048);  // [768,768]
    unsigned short* w1b   = (unsigned short*)(ws + 61341696);  // [3072,768]
    unsigned short* w2b   = (unsigned short*)(ws + 66060288);  // [768,3072]
    float*          bqkv  = (float*)(ws + 70778880);           // [2304] f32

    dim3 blk(256);

    // all conversions + bias pack in one launch
    conv_fused<<<dim3(9985), blk, 0, stream>>>(
        x, Wq, Wk, Wv, Wp, W1, W2, bq, bk, bv,
        xb, wqkvb, wpb, w1b, w2b, bqkv);

    // fused QKV GEMM -> bf16: qkvb[M,2304]
    gemm_bf16<<<dim3(QKV_LD / 128, M / 128), blk, 0, stream>>>(
        xb, D_MODEL, wqkvb, D_MODEL, bqkv, nullptr, 0,
        nullptr, qkvb, QKV_LD, M, QKV_LD, D_MODEL, 3);

    // MFMA flash attention -> hb (bf16)
    attn_mfma<<<dim3(SEQ / 64, BATCH * N_HEAD), blk, 0, stream>>>(qkvb, mask, hb);

    // proj + residual: y0 = hb @ wpb^T + bp + x
    gemm_bf16<<<dim3(D_MODEL / 128, M / 128), blk, 0, stream>>>(
        hb, D_MODEL, wpb, D_MODEL, bp, x, D_MODEL,
        y0, nullptr, D_MODEL, M, D_MODEL, D_MODEL, 1);

    // LN1 -> x1 (f32) + x1b (bf16)
    ln_kernel<<<dim3(M), blk, 0, stream>>>(y0, g1, be1, x1, x1b);

    // FFN1 + gelu -> ff1b (bf16)
    gemm_bf16<<<dim3(D_FF / 128, M / 128), blk, 0, stream>>>(
        x1b, D_MODEL, w1b, D_MODEL, bf1, nullptr, 0,
        nullptr, ff1b, D_FF, M, D_FF, D_MODEL, 2);

    // FFN2 + residual: y1 = ff1b @ w2b^T + bf2 + x1  (into y0)
    gemm_bf16<<<dim3(D_MODEL / 128, M / 128), blk, 0, stream>>>(
        ff1b, D_FF, w2b, D_FF, bf2, x1, D_MODEL,
        y0, nullptr, D_MODEL, M, D_MODEL, D_FF, 1);

    // LN2 -> out (f32)
    ln_kernel<<<dim3(M), blk, 0, stream>>>(y0, g2, be2, (float*)d_out, nullptr);
}

// Round 5
// 392.973 us; speedup vs baseline: 18.3239x; 1.1186x over previous
//
#include <hip/hip_runtime.h>
#include <hip/hip_bf16.h>
#include <math.h>

// Problem constants
#define D_MODEL 768
#define D_FF    3072
#define N_HEAD  12
#define HEAD_D  64
#define BATCH   2
#define SEQ     2048
#define QKV_LD  2304

typedef __attribute__((ext_vector_type(8))) short short8;            // 8 bf16 (4 VGPRs)
typedef __attribute__((ext_vector_type(8))) unsigned short ushort8;  // 16B staging
typedef __attribute__((ext_vector_type(4))) float f32x4;             // MFMA C/D frag

__device__ inline unsigned short f2bf(float f) {
    union { __hip_bfloat16 b; unsigned short u; } cv;
    cv.b = __float2bfloat16(f);
    return cv.u;
}

__device__ inline float bf2f(unsigned short u) {
    union { unsigned int i; float f; } cv;
    cv.i = ((unsigned int)u) << 16;
    return cv.f;
}

__device__ inline void async_load16(const void* g, void* l) {
    __builtin_amdgcn_global_load_lds(
        (const __attribute__((address_space(1))) void*)g,
        (__attribute__((address_space(3))) void*)l, 16, 0, 0);
}

// ---------------- fused fp32->bf16 conversions + bias pack -------------------------
__global__ __launch_bounds__(256) void conv_fused(
    const float* __restrict__ x,
    const float* __restrict__ Wq, const float* __restrict__ Wk,
    const float* __restrict__ Wv, const float* __restrict__ Wp,
    const float* __restrict__ W1, const float* __restrict__ W2,
    const float* __restrict__ bq, const float* __restrict__ bk,
    const float* __restrict__ bv,
    unsigned short* __restrict__ xb, unsigned short* __restrict__ wqkvb,
    unsigned short* __restrict__ wpb, unsigned short* __restrict__ w1b,
    unsigned short* __restrict__ w2b, float* __restrict__ bqkv)
{
    int bid = blockIdx.x;
    const float* src; unsigned short* dst; int base;
    if      (bid < 3072) { src = x;  dst = xb;              base = bid;        }
    else if (bid < 3648) { src = Wq; dst = wqkvb;           base = bid - 3072; }
    else if (bid < 4224) { src = Wk; dst = wqkvb + 589824;  base = bid - 3648; }
    else if (bid < 4800) { src = Wv; dst = wqkvb + 1179648; base = bid - 4224; }
    else if (bid < 5376) { src = Wp; dst = wpb;             base = bid - 4800; }
    else if (bid < 7680) { src = W1; dst = w1b;             base = bid - 5376; }
    else if (bid < 9984) { src = W2; dst = w2b;             base = bid - 7680; }
    else {
        for (int j = threadIdx.x; j < QKV_LD; j += 256)
            bqkv[j] = (j < 768) ? bq[j] : (j < 1536) ? bk[j - 768] : bv[j - 1536];
        return;
    }
    int i = (base * 256 + threadIdx.x) * 4;
    float4 v = *(const float4*)(src + i);
    ushort4 o4;
    o4.x = f2bf(v.x); o4.y = f2bf(v.y); o4.z = f2bf(v.z); o4.w = f2bf(v.w);
    *(ushort4*)(dst + i) = o4;
}

// ---------------- bf16 MFMA GEMM (m97 structure) -----------------------------------
// C[m,n] = sum_k A[m,k]*W[n,k]; A:[M,K] bf16, W:[N,K] bf16 (NT).
// mode 0: outf = acc + bias
// mode 1: outf = acc + bias + bf16(resb)
// mode 2: outb = bf16(gelu_exact(acc + bias))
// mode 3: outb = bf16(acc + bias)
__global__ __launch_bounds__(256) void gemm_bf16(
    const unsigned short* __restrict__ A, int lda,
    const unsigned short* __restrict__ W, int ldw,
    const float* __restrict__ bias,
    const unsigned short* __restrict__ resb, int ldr,
    float* __restrict__ outf, unsigned short* __restrict__ outb, int ldo,
    int M, int N, int K, int mode)
{
    __shared__ unsigned short As[128 * 32];
    __shared__ unsigned short Bs[128 * 32];

    const int t    = threadIdx.x;
    const int lane = t & 63;
    const int wv   = t >> 6;
    const int wm   = wv >> 1;
    const int wn   = wv & 1;
    const int bm   = blockIdx.y * 128;
    const int bn   = blockIdx.x * 128;

    const int qd   = lane >> 4;
    const int l16  = lane & 15;

    f32x4 acc[4][4];
    #pragma unroll
    for (int i = 0; i < 4; i++)
        #pragma unroll
        for (int j = 0; j < 4; j++)
            acc[i][j] = (f32x4){0.f, 0.f, 0.f, 0.f};

    const int srow = lane >> 2;
    const int sseg = (lane & 3) * 8;

    for (int k0 = 0; k0 < K; k0 += 32) {
        #pragma unroll
        for (int i = 0; i < 2; i++) {
            int c = wv * 2 + i;
            int r = c * 16 + srow;
            async_load16(A + (size_t)(bm + r) * lda + k0 + sseg, As + c * 512);
            async_load16(W + (size_t)(bn + r) * ldw + k0 + sseg, Bs + c * 512);
        }
        __syncthreads();

        short8 af[4], bf[4];
        #pragma unroll
        for (int mt = 0; mt < 4; mt++)
            af[mt] = *(const short8*)(As + (wm * 64 + mt * 16 + l16) * 32 + qd * 8);
        #pragma unroll
        for (int nt = 0; nt < 4; nt++)
            bf[nt] = *(const short8*)(Bs + (wn * 64 + nt * 16 + l16) * 32 + qd * 8);
        #pragma unroll
        for (int mt = 0; mt < 4; mt++)
            #pragma unroll
            for (int nt = 0; nt < 4; nt++)
                acc[mt][nt] = __builtin_amdgcn_mfma_f32_16x16x32_bf16(
                    af[mt], bf[nt], acc[mt][nt], 0, 0, 0);
        __syncthreads();
    }

    #pragma unroll
    for (int mt = 0; mt < 4; mt++) {
        #pragma unroll
        for (int nt = 0; nt < 4; nt++) {
            int col = bn + wn * 64 + nt * 16 + l16;
            float bv = bias[col];
            #pragma unroll
            for (int r = 0; r < 4; r++) {
                int row = bm + wm * 64 + mt * 16 + qd * 4 + r;
                float v = acc[mt][nt][r] + bv;
                if (mode == 1) {
                    v += bf2f(resb[(size_t)row * ldr + col]);
                    outf[(size_t)row * ldo + col] = v;
                } else if (mode == 2) {
                    v = 0.5f * v * (1.0f + erff(v * 0.70710678118654752f));
                    outb[(size_t)row * ldo + col] = f2bf(v);
                } else if (mode == 3) {
                    outb[(size_t)row * ldo + col] = f2bf(v);
                } else {
                    outf[(size_t)row * ldo + col] = v;
                }
            }
        }
    }
}

// ---------------- MFMA flash attention, S^T form (P stays in registers) ------------
// Per key-tile: S^T = K·Q^T with key-slot permutation sigma so each lane's 4 C-regs
// x 2 blocks = keys quad*8..+7 == the A-operand layout of 16x16x32 for PV.
// V^T staged with XOR swizzle slot = key ^ 8*(dim>>4): transpose stores 2-way only.
#define ASTR 72

__global__ __launch_bounds__(256) void attn_mfma(
    const unsigned short* __restrict__ qkv, const float* __restrict__ mask,
    unsigned short* __restrict__ out)
{
    __shared__ __align__(16) unsigned short Ks[64 * ASTR];
    __shared__ __align__(16) unsigned short Vt[64 * ASTR];
    __shared__ float Ms[64];

    const int t    = threadIdx.x;
    const int lane = t & 63;
    const int wv   = t >> 6;
    const int l16  = lane & 15;
    const int quad = lane >> 4;
    const int q0   = blockIdx.x * 64;
    const int bh   = blockIdx.y;
    const int h    = bh % N_HEAD;
    const int b    = bh / N_HEAD;

    const unsigned short* qb = qkv + (size_t)b * SEQ * QKV_LD + h * HEAD_D;
    const unsigned short* kb = qb + 768;
    const unsigned short* vb = qb + 1536;

    const int srow = t >> 2;          // staged row (key / query index 0..63)
    const int sc0  = (t & 3) * 16;    // dim start
    // sigma: key = w<<5|q<<3|bsel<<2|r  ->  slot = w<<5|bsel<<4|q<<2|r
    const int sigrow = (srow & 0x23) | ((srow & 0x04) << 2) | ((srow & 0x18) >> 1);
    const int vslot  = srow ^ ((t & 3) << 3);   // dim>>4 == t&3 for this thread

    // ---- stage Q tile (natural rows), pull Q B-frags (lane l16 = query) ----
    {
        const ushort8* src = (const ushort8*)(qb + (size_t)(q0 + srow) * QKV_LD + sc0);
        *(ushort8*)&Ks[srow * ASTR + sc0]     = src[0];
        *(ushort8*)&Ks[srow * ASTR + sc0 + 8] = src[1];
    }
    __syncthreads();
    short8 bq0 = *(const short8*)&Ks[(wv * 16 + l16) * ASTR + quad * 8];
    short8 bq1 = *(const short8*)&Ks[(wv * 16 + l16) * ASTR + 32 + quad * 8];
    __syncthreads();

    f32x4 o[4];
    #pragma unroll
    for (int i = 0; i < 4; i++) o[i] = (f32x4){0.f, 0.f, 0.f, 0.f};
    float m_st = -INFINITY, l_st = 0.f;

    for (int kt = 0; kt < SEQ / 64; kt++) {
        const int key0 = kt * 64;
        // ---- stage K (sigma-permuted rows) + V^T (XOR-swizzled slots) + mask ----
        {
            const ushort8* ksrc = (const ushort8*)(kb + (size_t)(key0 + srow) * QKV_LD + sc0);
            *(ushort8*)&Ks[sigrow * ASTR + sc0]     = ksrc[0];
            *(ushort8*)&Ks[sigrow * ASTR + sc0 + 8] = ksrc[1];
            const ushort8* vsrc = (const ushort8*)(vb + (size_t)(key0 + srow) * QKV_LD + sc0);
            ushort8 v0 = vsrc[0], v1 = vsrc[1];
            #pragma unroll
            for (int j = 0; j < 8; j++) Vt[(sc0 + j) * ASTR + vslot] = v0[j];
            #pragma unroll
            for (int j = 0; j < 8; j++) Vt[(sc0 + 8 + j) * ASTR + vslot] = v1[j];
            if (t < 64) Ms[t] = -10000.0f * (1.0f - mask[b * SEQ + key0 + t]);
        }
        __syncthreads();

        // ---- S^T = K·Q^T over 4 slot-blocks (A = K, B = Q) ----
        f32x4 st[4];
        #pragma unroll
        for (int bi = 0; bi < 4; bi++) {
            const int krow = (bi * 16 + l16) * ASTR;
            short8 k0 = *(const short8*)&Ks[krow + quad * 8];
            short8 k1 = *(const short8*)&Ks[krow + 32 + quad * 8];
            f32x4 z = (f32x4){0.f, 0.f, 0.f, 0.f};
            z = __builtin_amdgcn_mfma_f32_16x16x32_bf16(k0, bq0, z, 0, 0, 0);
            st[bi] = __builtin_amdgcn_mfma_f32_16x16x32_bf16(k1, bq1, z, 0, 0, 0);
        }

        // ---- online softmax: lane owns query l16, 16 keys (quad*8..+7 per window) --
        float p[4][4];
        float mx = -3.0e38f;
        #pragma unroll
        for (int bi = 0; bi < 4; bi++) {
            #pragma unroll
            for (int r = 0; r < 4; r++) {
                float s = fmaf(st[bi][r], 0.125f,
                               Ms[((bi >> 1) << 5) + (quad << 3) + ((bi & 1) << 2) + r]);
                p[bi][r] = s;
                mx = fmaxf(mx, s);
            }
        }
        mx = fmaxf(mx, __shfl_xor(mx, 16, 64));
        mx = fmaxf(mx, __shfl_xor(mx, 32, 64));
        float m_new = fmaxf(m_st, mx);
        float alpha = __expf(m_st - m_new);   // first tile: exp(-inf)=0
        m_st = m_new;
        float ls = 0.f;
        #pragma unroll
        for (int bi = 0; bi < 4; bi++) {
            #pragma unroll
            for (int r = 0; r < 4; r++) {
                p[bi][r] = __expf(p[bi][r] - m_new);
                ls += p[bi][r];
            }
        }
        ls += __shfl_xor(ls, 16, 64);
        ls += __shfl_xor(ls, 32, 64);
        l_st = l_st * alpha + ls;

        // ---- broadcast alpha per C-row query, rescale O ----
        float ar[4];
        #pragma unroll
        for (int r = 0; r < 4; r++) ar[r] = __shfl(alpha, quad * 4 + r, 64);
        #pragma unroll
        for (int nt = 0; nt < 4; nt++)
            #pragma unroll
            for (int r = 0; r < 4; r++)
                o[nt][r] *= ar[r];

        // ---- P frags in registers (A-layout: k = quad*8 + bsel*4 + r) ----
        short8 pf0, pf1;
        #pragma unroll
        for (int bsel = 0; bsel < 2; bsel++) {
            #pragma unroll
            for (int r = 0; r < 4; r++) {
                pf0[bsel * 4 + r] = (short)f2bf(p[bsel][r]);
                pf1[bsel * 4 + r] = (short)f2bf(p[2 + bsel][r]);
            }
        }

        // ---- PV: O += P · V  (B-frags from swizzled V^T) ----
        #pragma unroll
        for (int nt = 0; nt < 4; nt++) {
            const int vrow = (nt * 16 + l16) * ASTR;
            short8 v0 = *(const short8*)&Vt[vrow + ((quad * 8) ^ (nt << 3))];
            short8 v1 = *(const short8*)&Vt[vrow + ((32 + quad * 8) ^ (nt << 3))];
            o[nt] = __builtin_amdgcn_mfma_f32_16x16x32_bf16(pf0, v0, o[nt], 0, 0, 0);
            o[nt] = __builtin_amdgcn_mfma_f32_16x16x32_bf16(pf1, v1, o[nt], 0, 0, 0);
        }
        __syncthreads();
    }

    // ---- epilogue: out[b, q0+wv*16+quad*4+r, h*64 + nt*16 + l16] = O / l ----
    float inv = 1.0f / l_st;
    float ir[4];
    #pragma unroll
    for (int r = 0; r < 4; r++) ir[r] = __shfl(inv, quad * 4 + r, 64);
    #pragma unroll
    for (int nt = 0; nt < 4; nt++) {
        #pragma unroll
        for (int r = 0; r < 4; r++) {
            int qi = q0 + wv * 16 + quad * 4 + r;
            out[(size_t)(b * SEQ + qi) * D_MODEL + h * HEAD_D + nt * 16 + l16] =
                f2bf(o[nt][r] * ir[r]);
        }
    }
}

// ---------------- LayerNorm over 768; f32 and/or bf16 outputs (nullable) -----------
__global__ __launch_bounds__(256) void ln_kernel(
    const float* __restrict__ in, const float* __restrict__ g,
    const float* __restrict__ be, float* __restrict__ outf,
    unsigned short* __restrict__ outb)
{
    const int row = blockIdx.x;
    const int t   = threadIdx.x;
    const float* rp = in + (size_t)row * D_MODEL;

    float vals[3];
    float s = 0.f, s2 = 0.f;
    #pragma unroll
    for (int i = 0; i < 3; i++) {
        float x = rp[t + i * 256];
        vals[i] = x;
        s += x; s2 += x * x;
    }
    #pragma unroll
    for (int off = 32; off >= 1; off >>= 1) {
        s  += __shfl_xor(s,  off, 64);
        s2 += __shfl_xor(s2, off, 64);
    }
    __shared__ float rs[4], rs2[4];
    __shared__ float mu_s, rstd_s;
    const int wave = t >> 6, lane = t & 63;
    if (lane == 0) { rs[wave] = s; rs2[wave] = s2; }
    __syncthreads();
    if (t == 0) {
        float S1 = rs[0] + rs[1] + rs[2] + rs[3];
        float S2 = rs2[0] + rs2[1] + rs2[2] + rs2[3];
        float mu  = S1 * (1.0f / D_MODEL);
        float var = S2 * (1.0f / D_MODEL) - mu * mu;
        mu_s = mu;
        rstd_s = rsqrtf(var + 1e-12f);
    }
    __syncthreads();
    const float mu = mu_s, rstd = rstd_s;
    #pragma unroll
    for (int i = 0; i < 3; i++) {
        int c = t + i * 256;
        float o = g[c] * (vals[i] - mu) * rstd + be[c];
        if (outf) outf[(size_t)row * D_MODEL + c] = o;
        if (outb) outb[(size_t)row * D_MODEL + c] = f2bf(o);
    }
}

extern "C" void kernel_launch(void* const* d_in, const int* in_sizes, int n_in,
                              void* d_out, int out_size, void* d_ws, size_t ws_size,
                              hipStream_t stream)
{
    const float* x    = (const float*)d_in[0];
    const float* mask = (const float*)d_in[1];
    const float* Wq   = (const float*)d_in[2];
    const float* bq   = (const float*)d_in[3];
    const float* Wk   = (const float*)d_in[4];
    const float* bk   = (const float*)d_in[5];
    const float* Wv   = (const float*)d_in[6];
    const float* bv   = (const float*)d_in[7];
    const float* Wp   = (const float*)d_in[8];
    const float* bp   = (const float*)d_in[9];
    const float* g1   = (const float*)d_in[10];
    const float* be1  = (const float*)d_in[11];
    const float* W1   = (const float*)d_in[12];
    const float* bf1  = (const float*)d_in[13];
    const float* W2   = (const float*)d_in[14];
    const float* bf2  = (const float*)d_in[15];
    const float* g2   = (const float*)d_in[16];
    const float* be2  = (const float*)d_in[17];

    const int M = BATCH * SEQ;   // 4096

    // ---- workspace layout (bytes), ~64.5 MB total ----
    char* ws = (char*)d_ws;
    unsigned short* qkvb  = (unsigned short*)(ws + 0);         // [4096,2304] bf16
    unsigned short* ff1b  = (unsigned short*)(ws + 0);         // [4096,3072] bf16 (qkvb dead)
    unsigned short* xb    = (unsigned short*)(ws + 25165824);  // [4096,768] bf16 (live thru proj)
    unsigned short* hb    = (unsigned short*)(ws + 31457280);  // [4096,768] bf16
    unsigned short* x1b   = (unsigned short*)(ws + 31457280);  // alias (hb dead after proj)
    float*          y0    = (float*)(ws + 37748736);           // [4096,768] f32 (LN input, reused)
    unsigned short* wqkvb = (unsigned short*)(ws + 50331648);  // [2304,768]
    unsigned short* wpb   = (unsigned short*)(ws + 53870592);  // [768,768]
    unsigned short* w1b   = (unsigned short*)(ws + 55050240);  // [3072,768]
    unsigned short* w2b   = (unsigned short*)(ws + 59768832);  // [768,3072]
    float*          bqkv  = (float*)(ws + 64487424);           // [2304]

    dim3 blk(256);

    conv_fused<<<dim3(9985), blk, 0, stream>>>(
        x, Wq, Wk, Wv, Wp, W1, W2, bq, bk, bv,
        xb, wqkvb, wpb, w1b, w2b, bqkv);

    // fused QKV GEMM -> bf16
    gemm_bf16<<<dim3(QKV_LD / 128, M / 128), blk, 0, stream>>>(
        xb, D_MODEL, wqkvb, D_MODEL, bqkv, nullptr, 0,
        nullptr, qkvb, QKV_LD, M, QKV_LD, D_MODEL, 3);

    // flash attention -> hb (bf16)
    attn_mfma<<<dim3(SEQ / 64, BATCH * N_HEAD), blk, 0, stream>>>(qkvb, mask, hb);

    // proj + residual (bf16 x): y0 = hb @ wpb^T + bp + xb
    gemm_bf16<<<dim3(D_MODEL / 128, M / 128), blk, 0, stream>>>(
        hb, D_MODEL, wpb, D_MODEL, bp, xb, D_MODEL,
        y0, nullptr, D_MODEL, M, D_MODEL, D_MODEL, 1);

    // LN1 -> x1b (bf16 only)
    ln_kernel<<<dim3(M), blk, 0, stream>>>(y0, g1, be1, nullptr, x1b);

    // FFN1 + gelu -> ff1b
    gemm_bf16<<<dim3(D_FF / 128, M / 128), blk, 0, stream>>>(
        x1b, D_MODEL, w1b, D_MODEL, bf1, nullptr, 0,
        nullptr, ff1b, D_FF, M, D_FF, D_MODEL, 2);

    // FFN2 + residual (bf16 x1): y1 = ff1b @ w2b^T + bf2 + x1b  (into y0)
    gemm_bf16<<<dim3(D_MODEL / 128, M / 128), blk, 0, stream>>>(
        ff1b, D_FF, w2b, D_FF, bf2, x1b, D_MODEL,
        y0, nullptr, D_MODEL, M, D_MODEL, D_FF, 1);

    // LN2 -> out (f32)
    ln_kernel<<<dim3(M), blk, 0, stream>>>(y0, g2, be2, (float*)d_out, nullptr);
}

// Round 6
// 385.434 us; speedup vs baseline: 18.6823x; 1.0196x over previous
//
#include <hip/hip_runtime.h>
#include <hip/hip_bf16.h>
#include <math.h>

// Problem constants
#define D_MODEL 768
#define D_FF    3072
#define N_HEAD  12
#define HEAD_D  64
#define BATCH   2
#define SEQ     2048
#define QKV_LD  2304

typedef __attribute__((ext_vector_type(8))) short short8;            // 8 bf16 (4 VGPRs)
typedef __attribute__((ext_vector_type(8))) unsigned short ushort8;  // 16B staging
typedef __attribute__((ext_vector_type(4))) float f32x4;             // MFMA C/D frag

__device__ inline unsigned short f2bf(float f) {
    union { __hip_bfloat16 b; unsigned short u; } cv;
    cv.b = __float2bfloat16(f);
    return cv.u;
}

__device__ inline float bf2f(unsigned short u) {
    union { unsigned int i; float f; } cv;
    cv.i = ((unsigned int)u) << 16;
    return cv.f;
}

__device__ inline void async_load16(const void* g, void* l) {
    __builtin_amdgcn_global_load_lds(
        (const __attribute__((address_space(1))) void*)g,
        (__attribute__((address_space(3))) void*)l, 16, 0, 0);
}

// ---------------- fused fp32->bf16 conversions + bias pack -------------------------
__global__ __launch_bounds__(256) void conv_fused(
    const float* __restrict__ x,
    const float* __restrict__ Wq, const float* __restrict__ Wk,
    const float* __restrict__ Wv, const float* __restrict__ Wp,
    const float* __restrict__ W1, const float* __restrict__ W2,
    const float* __restrict__ bq, const float* __restrict__ bk,
    const float* __restrict__ bv,
    unsigned short* __restrict__ xb, unsigned short* __restrict__ wqkvb,
    unsigned short* __restrict__ wpb, unsigned short* __restrict__ w1b,
    unsigned short* __restrict__ w2b, float* __restrict__ bqkv)
{
    int bid = blockIdx.x;
    const float* src; unsigned short* dst; int base;
    if      (bid < 3072) { src = x;  dst = xb;              base = bid;        }
    else if (bid < 3648) { src = Wq; dst = wqkvb;           base = bid - 3072; }
    else if (bid < 4224) { src = Wk; dst = wqkvb + 589824;  base = bid - 3648; }
    else if (bid < 4800) { src = Wv; dst = wqkvb + 1179648; base = bid - 4224; }
    else if (bid < 5376) { src = Wp; dst = wpb;             base = bid - 4800; }
    else if (bid < 7680) { src = W1; dst = w1b;             base = bid - 5376; }
    else if (bid < 9984) { src = W2; dst = w2b;             base = bid - 7680; }
    else {
        for (int j = threadIdx.x; j < QKV_LD; j += 256)
            bqkv[j] = (j < 768) ? bq[j] : (j < 1536) ? bk[j - 768] : bv[j - 1536];
        return;
    }
    int i = (base * 256 + threadIdx.x) * 4;
    float4 v = *(const float4*)(src + i);
    ushort4 o4;
    o4.x = f2bf(v.x); o4.y = f2bf(v.y); o4.z = f2bf(v.z); o4.w = f2bf(v.w);
    *(ushort4*)(dst + i) = o4;
}

// ---------------- bf16 MFMA GEMM (m97 structure) + optional split-K ---------------
// C[m,n] = sum_k A[m,k]*W[n,k]; A:[M,K] bf16, W:[N,K] bf16 (NT).
// gridDim.z = number of K-splits. Block z covers k in [z*K/gz, (z+1)*K/gz).
//   z == 0 : epilogue per mode (bias / bias+res / gelu / bf16)
//   z  > 0 : raw f32 partial into pacc (summed later by ln_kernel)
// mode 0: outf = acc + bias
// mode 1: outf = acc + bias + bf16(resb)
// mode 2: outb = bf16(gelu_exact(acc + bias))   (do not split-K)
// mode 3: outb = bf16(acc + bias)
__global__ __launch_bounds__(256) void gemm_bf16(
    const unsigned short* __restrict__ A, int lda,
    const unsigned short* __restrict__ W, int ldw,
    const float* __restrict__ bias,
    const unsigned short* __restrict__ resb, int ldr,
    float* __restrict__ outf, unsigned short* __restrict__ outb,
    float* __restrict__ pacc, int ldo,
    int M, int N, int K, int mode)
{
    __shared__ unsigned short As[128 * 32];
    __shared__ unsigned short Bs[128 * 32];

    const int t    = threadIdx.x;
    const int lane = t & 63;
    const int wv   = t >> 6;
    const int wm   = wv >> 1;
    const int wn   = wv & 1;
    const int bm   = blockIdx.y * 128;
    const int bn   = blockIdx.x * 128;
    const int kz   = blockIdx.z;
    const int Kc   = K / gridDim.z;

    const int qd   = lane >> 4;
    const int l16  = lane & 15;

    f32x4 acc[4][4];
    #pragma unroll
    for (int i = 0; i < 4; i++)
        #pragma unroll
        for (int j = 0; j < 4; j++)
            acc[i][j] = (f32x4){0.f, 0.f, 0.f, 0.f};

    const int srow = lane >> 2;
    const int sseg = (lane & 3) * 8;

    const int kbeg = kz * Kc, kend = kbeg + Kc;
    for (int k0 = kbeg; k0 < kend; k0 += 32) {
        #pragma unroll
        for (int i = 0; i < 2; i++) {
            int c = wv * 2 + i;
            int r = c * 16 + srow;
            async_load16(A + (size_t)(bm + r) * lda + k0 + sseg, As + c * 512);
            async_load16(W + (size_t)(bn + r) * ldw + k0 + sseg, Bs + c * 512);
        }
        __syncthreads();

        short8 af[4], bf[4];
        #pragma unroll
        for (int mt = 0; mt < 4; mt++)
            af[mt] = *(const short8*)(As + (wm * 64 + mt * 16 + l16) * 32 + qd * 8);
        #pragma unroll
        for (int nt = 0; nt < 4; nt++)
            bf[nt] = *(const short8*)(Bs + (wn * 64 + nt * 16 + l16) * 32 + qd * 8);
        #pragma unroll
        for (int mt = 0; mt < 4; mt++)
            #pragma unroll
            for (int nt = 0; nt < 4; nt++)
                acc[mt][nt] = __builtin_amdgcn_mfma_f32_16x16x32_bf16(
                    af[mt], bf[nt], acc[mt][nt], 0, 0, 0);
        __syncthreads();
    }

    #pragma unroll
    for (int mt = 0; mt < 4; mt++) {
        #pragma unroll
        for (int nt = 0; nt < 4; nt++) {
            int col = bn + wn * 64 + nt * 16 + l16;
            float bv = (kz == 0) ? bias[col] : 0.f;
            #pragma unroll
            for (int r = 0; r < 4; r++) {
                int row = bm + wm * 64 + mt * 16 + qd * 4 + r;
                if (kz != 0) {
                    pacc[(size_t)row * ldo + col] = acc[mt][nt][r];
                    continue;
                }
                float v = acc[mt][nt][r] + bv;
                if (mode == 1) {
                    v += bf2f(resb[(size_t)row * ldr + col]);
                    outf[(size_t)row * ldo + col] = v;
                } else if (mode == 2) {
                    v = 0.5f * v * (1.0f + erff(v * 0.70710678118654752f));
                    outb[(size_t)row * ldo + col] = f2bf(v);
                } else if (mode == 3) {
                    outb[(size_t)row * ldo + col] = f2bf(v);
                } else {
                    outf[(size_t)row * ldo + col] = v;
                }
            }
        }
    }
}

// ---------------- MFMA flash attention, S^T form (P stays in registers) ------------
#define ASTR 72

__global__ __launch_bounds__(256) void attn_mfma(
    const unsigned short* __restrict__ qkv, const float* __restrict__ mask,
    unsigned short* __restrict__ out)
{
    __shared__ __align__(16) unsigned short Ks[64 * ASTR];
    __shared__ __align__(16) unsigned short Vt[64 * ASTR];
    __shared__ float Ms[64];

    const int t    = threadIdx.x;
    const int lane = t & 63;
    const int wv   = t >> 6;
    const int l16  = lane & 15;
    const int quad = lane >> 4;
    const int q0   = blockIdx.x * 64;
    const int bh   = blockIdx.y;
    const int h    = bh % N_HEAD;
    const int b    = bh / N_HEAD;

    const unsigned short* qb = qkv + (size_t)b * SEQ * QKV_LD + h * HEAD_D;
    const unsigned short* kb = qb + 768;
    const unsigned short* vb = qb + 1536;

    const int srow = t >> 2;
    const int sc0  = (t & 3) * 16;
    const int sigrow = (srow & 0x23) | ((srow & 0x04) << 2) | ((srow & 0x18) >> 1);
    const int vslot  = srow ^ ((t & 3) << 3);

    {
        const ushort8* src = (const ushort8*)(qb + (size_t)(q0 + srow) * QKV_LD + sc0);
        *(ushort8*)&Ks[srow * ASTR + sc0]     = src[0];
        *(ushort8*)&Ks[srow * ASTR + sc0 + 8] = src[1];
    }
    __syncthreads();
    short8 bq0 = *(const short8*)&Ks[(wv * 16 + l16) * ASTR + quad * 8];
    short8 bq1 = *(const short8*)&Ks[(wv * 16 + l16) * ASTR + 32 + quad * 8];
    __syncthreads();

    f32x4 o[4];
    #pragma unroll
    for (int i = 0; i < 4; i++) o[i] = (f32x4){0.f, 0.f, 0.f, 0.f};
    float m_st = -INFINITY, l_st = 0.f;

    for (int kt = 0; kt < SEQ / 64; kt++) {
        const int key0 = kt * 64;
        {
            const ushort8* ksrc = (const ushort8*)(kb + (size_t)(key0 + srow) * QKV_LD + sc0);
            *(ushort8*)&Ks[sigrow * ASTR + sc0]     = ksrc[0];
            *(ushort8*)&Ks[sigrow * ASTR + sc0 + 8] = ksrc[1];
            const ushort8* vsrc = (const ushort8*)(vb + (size_t)(key0 + srow) * QKV_LD + sc0);
            ushort8 v0 = vsrc[0], v1 = vsrc[1];
            #pragma unroll
            for (int j = 0; j < 8; j++) Vt[(sc0 + j) * ASTR + vslot] = v0[j];
            #pragma unroll
            for (int j = 0; j < 8; j++) Vt[(sc0 + 8 + j) * ASTR + vslot] = v1[j];
            if (t < 64) Ms[t] = -10000.0f * (1.0f - mask[b * SEQ + key0 + t]);
        }
        __syncthreads();

        f32x4 st[4];
        #pragma unroll
        for (int bi = 0; bi < 4; bi++) {
            const int krow = (bi * 16 + l16) * ASTR;
            short8 k0 = *(const short8*)&Ks[krow + quad * 8];
            short8 k1 = *(const short8*)&Ks[krow + 32 + quad * 8];
            f32x4 z = (f32x4){0.f, 0.f, 0.f, 0.f};
            z = __builtin_amdgcn_mfma_f32_16x16x32_bf16(k0, bq0, z, 0, 0, 0);
            st[bi] = __builtin_amdgcn_mfma_f32_16x16x32_bf16(k1, bq1, z, 0, 0, 0);
        }

        float p[4][4];
        float mx = -3.0e38f;
        #pragma unroll
        for (int bi = 0; bi < 4; bi++) {
            #pragma unroll
            for (int r = 0; r < 4; r++) {
                float s = fmaf(st[bi][r], 0.125f,
                               Ms[((bi >> 1) << 5) + (quad << 3) + ((bi & 1) << 2) + r]);
                p[bi][r] = s;
                mx = fmaxf(mx, s);
            }
        }
        mx = fmaxf(mx, __shfl_xor(mx, 16, 64));
        mx = fmaxf(mx, __shfl_xor(mx, 32, 64));
        float m_new = fmaxf(m_st, mx);
        float alpha = __expf(m_st - m_new);
        m_st = m_new;
        float ls = 0.f;
        #pragma unroll
        for (int bi = 0; bi < 4; bi++) {
            #pragma unroll
            for (int r = 0; r < 4; r++) {
                p[bi][r] = __expf(p[bi][r] - m_new);
                ls += p[bi][r];
            }
        }
        ls += __shfl_xor(ls, 16, 64);
        ls += __shfl_xor(ls, 32, 64);
        l_st = l_st * alpha + ls;

        float ar[4];
        #pragma unroll
        for (int r = 0; r < 4; r++) ar[r] = __shfl(alpha, quad * 4 + r, 64);
        #pragma unroll
        for (int nt = 0; nt < 4; nt++)
            #pragma unroll
            for (int r = 0; r < 4; r++)
                o[nt][r] *= ar[r];

        short8 pf0, pf1;
        #pragma unroll
        for (int bsel = 0; bsel < 2; bsel++) {
            #pragma unroll
            for (int r = 0; r < 4; r++) {
                pf0[bsel * 4 + r] = (short)f2bf(p[bsel][r]);
                pf1[bsel * 4 + r] = (short)f2bf(p[2 + bsel][r]);
            }
        }

        #pragma unroll
        for (int nt = 0; nt < 4; nt++) {
            const int vrow = (nt * 16 + l16) * ASTR;
            short8 v0 = *(const short8*)&Vt[vrow + ((quad * 8) ^ (nt << 3))];
            short8 v1 = *(const short8*)&Vt[vrow + ((32 + quad * 8) ^ (nt << 3))];
            o[nt] = __builtin_amdgcn_mfma_f32_16x16x32_bf16(pf0, v0, o[nt], 0, 0, 0);
            o[nt] = __builtin_amdgcn_mfma_f32_16x16x32_bf16(pf1, v1, o[nt], 0, 0, 0);
        }
        __syncthreads();
    }

    float inv = 1.0f / l_st;
    float ir[4];
    #pragma unroll
    for (int r = 0; r < 4; r++) ir[r] = __shfl(inv, quad * 4 + r, 64);
    #pragma unroll
    for (int nt = 0; nt < 4; nt++) {
        #pragma unroll
        for (int r = 0; r < 4; r++) {
            int qi = q0 + wv * 16 + quad * 4 + r;
            out[(size_t)(b * SEQ + qi) * D_MODEL + h * HEAD_D + nt * 16 + l16] =
                f2bf(o[nt][r] * ir[r]);
        }
    }
}

// ---------------- LayerNorm over 768; optional second f32 input (split-K partial) --
__global__ __launch_bounds__(256) void ln_kernel(
    const float* __restrict__ in, const float* __restrict__ in2,
    const float* __restrict__ g, const float* __restrict__ be,
    float* __restrict__ outf, unsigned short* __restrict__ outb)
{
    const int row = blockIdx.x;
    const int t   = threadIdx.x;
    const float* rp  = in  + (size_t)row * D_MODEL;
    const float* rp2 = in2 ? in2 + (size_t)row * D_MODEL : nullptr;

    float vals[3];
    float s = 0.f, s2 = 0.f;
    #pragma unroll
    for (int i = 0; i < 3; i++) {
        float x = rp[t + i * 256];
        if (rp2) x += rp2[t + i * 256];
        vals[i] = x;
        s += x; s2 += x * x;
    }
    #pragma unroll
    for (int off = 32; off >= 1; off >>= 1) {
        s  += __shfl_xor(s,  off, 64);
        s2 += __shfl_xor(s2, off, 64);
    }
    __shared__ float rs[4], rs2[4];
    __shared__ float mu_s, rstd_s;
    const int wave = t >> 6, lane = t & 63;
    if (lane == 0) { rs[wave] = s; rs2[wave] = s2; }
    __syncthreads();
    if (t == 0) {
        float S1 = rs[0] + rs[1] + rs[2] + rs[3];
        float S2 = rs2[0] + rs2[1] + rs2[2] + rs2[3];
        float mu  = S1 * (1.0f / D_MODEL);
        float var = S2 * (1.0f / D_MODEL) - mu * mu;
        mu_s = mu;
        rstd_s = rsqrtf(var + 1e-12f);
    }
    __syncthreads();
    const float mu = mu_s, rstd = rstd_s;
    #pragma unroll
    for (int i = 0; i < 3; i++) {
        int c = t + i * 256;
        float o = g[c] * (vals[i] - mu) * rstd + be[c];
        if (outf) outf[(size_t)row * D_MODEL + c] = o;
        if (outb) outb[(size_t)row * D_MODEL + c] = f2bf(o);
    }
}

extern "C" void kernel_launch(void* const* d_in, const int* in_sizes, int n_in,
                              void* d_out, int out_size, void* d_ws, size_t ws_size,
                              hipStream_t stream)
{
    const float* x    = (const float*)d_in[0];
    const float* mask = (const float*)d_in[1];
    const float* Wq   = (const float*)d_in[2];
    const float* bq   = (const float*)d_in[3];
    const float* Wk   = (const float*)d_in[4];
    const float* bk   = (const float*)d_in[5];
    const float* Wv   = (const float*)d_in[6];
    const float* bv   = (const float*)d_in[7];
    const float* Wp   = (const float*)d_in[8];
    const float* bp   = (const float*)d_in[9];
    const float* g1   = (const float*)d_in[10];
    const float* be1  = (const float*)d_in[11];
    const float* W1   = (const float*)d_in[12];
    const float* bf1  = (const float*)d_in[13];
    const float* W2   = (const float*)d_in[14];
    const float* bf2  = (const float*)d_in[15];
    const float* g2   = (const float*)d_in[16];
    const float* be2  = (const float*)d_in[17];

    const int M = BATCH * SEQ;   // 4096

    // ---- workspace layout (bytes), ~77.1 MB total ----
    char* ws = (char*)d_ws;
    unsigned short* qkvb  = (unsigned short*)(ws + 0);         // [4096,2304] bf16
    unsigned short* ff1b  = (unsigned short*)(ws + 0);         // [4096,3072] bf16 (qkvb dead)
    unsigned short* xb    = (unsigned short*)(ws + 25165824);  // [4096,768] bf16 (live thru proj)
    unsigned short* hb    = (unsigned short*)(ws + 31457280);  // [4096,768] bf16
    unsigned short* x1b   = (unsigned short*)(ws + 31457280);  // alias (hb dead after proj)
    float*          y0    = (float*)(ws + 37748736);           // [4096,768] f32
    unsigned short* wqkvb = (unsigned short*)(ws + 50331648);  // [2304,768]
    unsigned short* wpb   = (unsigned short*)(ws + 53870592);  // [768,768]
    unsigned short* w1b   = (unsigned short*)(ws + 55050240);  // [3072,768]
    unsigned short* w2b   = (unsigned short*)(ws + 59768832);  // [768,3072]
    float*          bqkv  = (float*)(ws + 64487424);           // [2304]
    float*          p1    = (float*)(ws + 64496640);           // [4096,768] f32 split-K partial

    dim3 blk(256);

    conv_fused<<<dim3(9985), blk, 0, stream>>>(
        x, Wq, Wk, Wv, Wp, W1, W2, bq, bk, bv,
        xb, wqkvb, wpb, w1b, w2b, bqkv);

    // fused QKV GEMM -> bf16
    gemm_bf16<<<dim3(QKV_LD / 128, M / 128, 1), blk, 0, stream>>>(
        xb, D_MODEL, wqkvb, D_MODEL, bqkv, nullptr, 0,
        nullptr, qkvb, nullptr, QKV_LD, M, QKV_LD, D_MODEL, 3);

    // flash attention -> hb (bf16)
    attn_mfma<<<dim3(SEQ / 64, BATCH * N_HEAD), blk, 0, stream>>>(qkvb, mask, hb);

    // proj + residual, split-K x2: y0 (z=0: bias + xb) + p1 (z=1 raw)
    gemm_bf16<<<dim3(D_MODEL / 128, M / 128, 2), blk, 0, stream>>>(
        hb, D_MODEL, wpb, D_MODEL, bp, xb, D_MODEL,
        y0, nullptr, p1, D_MODEL, M, D_MODEL, D_MODEL, 1);

    // LN1 over (y0 + p1) -> x1b (bf16)
    ln_kernel<<<dim3(M), blk, 0, stream>>>(y0, p1, g1, be1, nullptr, x1b);

    // FFN1 + gelu -> ff1b (unsplit; gelu is nonlinear)
    gemm_bf16<<<dim3(D_FF / 128, M / 128, 1), blk, 0, stream>>>(
        x1b, D_MODEL, w1b, D_MODEL, bf1, nullptr, 0,
        nullptr, ff1b, nullptr, D_FF, M, D_FF, D_MODEL, 2);

    // FFN2 + residual, split-K x2: y0 (z=0: bias + x1b) + p1 (z=1 raw)
    gemm_bf16<<<dim3(D_MODEL / 128, M / 128, 2), blk, 0, stream>>>(
        ff1b, D_FF, w2b, D_FF, bf2, x1b, D_MODEL,
        y0, nullptr, p1, D_MODEL, M, D_MODEL, D_FF, 1);

    // LN2 over (y0 + p1) -> out (f32)
    ln_kernel<<<dim3(M), blk, 0, stream>>>(y0, p1, g2, be2, (float*)d_out, nullptr);
}